// Round 6
// baseline (383.499 us; speedup 1.0000x reference)
//
#include <hip/hip_runtime.h>
#include <hip/hip_bf16.h>
#include <math.h>

#define B_      2
#define S_      2048
#define D_      2048
#define H_      16
#define NOPE_D  64
#define ROPE_DD 32
#define V_DD    64
#define QRANK   768
#define KVRANK  256
#define ROWS    (B_ * S_)   // 4096

typedef __attribute__((ext_vector_type(8))) short short8;
typedef __attribute__((ext_vector_type(4))) float f32x4;
typedef __attribute__((ext_vector_type(4))) unsigned short ushort4v;
typedef __attribute__((ext_vector_type(2))) unsigned int uint2v;

__device__ __forceinline__ float bf2f(unsigned short u) {
  return __uint_as_float(((unsigned)u) << 16);
}
__device__ __forceinline__ unsigned short f2bf(float f) {  // RNE
  unsigned u = __float_as_uint(f);
  return (unsigned short)((u + 0x7fffu + ((u >> 16) & 1u)) >> 16);
}
__device__ __forceinline__ unsigned cvtpk_bf16(float lo, float hi) {
  unsigned r;
  asm("v_cvt_pk_bf16_f32 %0, %1, %2" : "=v"(r) : "v"(lo), "v"(hi));
  return r;
}

// ---------------------------------------------------------------------------
// cast fp32 -> bf16, 8 elems/thread
// ---------------------------------------------------------------------------
__global__ __launch_bounds__(256) void cast_to_bf16(const float* __restrict__ in,
                                                    unsigned short* __restrict__ out,
                                                    int n) {
  int i = (blockIdx.x * 256 + threadIdx.x) * 8;
  if (i >= n) return;
  float4 a = *(const float4*)(in + i);
  float4 b = *(const float4*)(in + i + 4);
  unsigned short r[8] = {f2bf(a.x), f2bf(a.y), f2bf(a.z), f2bf(a.w),
                         f2bf(b.x), f2bf(b.y), f2bf(b.z), f2bf(b.w)};
  *(ushort4v*)(out + i)     = *(ushort4v*)&r[0];
  *(ushort4v*)(out + i + 4) = *(ushort4v*)&r[4];
}

// ---------------------------------------------------------------------------
// transpose + cast: in [R][C] fp32 -> out [C][R] bf16.  R,C % 32 == 0.
// ---------------------------------------------------------------------------
__global__ __launch_bounds__(256) void transpose_cast(const float* __restrict__ in,
                                                      unsigned short* __restrict__ out,
                                                      int R, int C) {
  __shared__ unsigned short t[32][33];
  const int c0 = blockIdx.x * 32, r0 = blockIdx.y * 32;
  const int tx = threadIdx.x & 31, ty = threadIdx.x >> 5;  // ty 0..7
#pragma unroll
  for (int i = 0; i < 32; i += 8)
    t[ty + i][tx] = f2bf(in[(size_t)(r0 + ty + i) * C + c0 + tx]);
  __syncthreads();
#pragma unroll
  for (int i = 0; i < 32; i += 8)
    out[(size_t)(c0 + ty + i) * R + r0 + tx] = t[tx][ty + i];
}

// ---------------------------------------------------------------------------
// transpose bf16: in [R][C] -> out [C][R]
// ---------------------------------------------------------------------------
__global__ __launch_bounds__(256) void transpose_bf16(const unsigned short* __restrict__ in,
                                                      unsigned short* __restrict__ out,
                                                      int R, int C) {
  __shared__ unsigned short t[32][33];
  const int c0 = blockIdx.x * 32, r0 = blockIdx.y * 32;
  const int tx = threadIdx.x & 31, ty = threadIdx.x >> 5;
#pragma unroll
  for (int i = 0; i < 32; i += 8)
    t[ty + i][tx] = in[(size_t)(r0 + ty + i) * C + c0 + tx];
  __syncthreads();
#pragma unroll
  for (int i = 0; i < 32; i += 8)
    out[(size_t)(c0 + ty + i) * R + r0 + tx] = t[tx][ty + i];
}

// ---------------------------------------------------------------------------
// bf16 MFMA GEMM (TN): A [M][K] bf16, Bt [N][K] bf16, C [M][N] (f32 or bf16).
// M%128==0, N%128==0, K%32==0. 256 thr = 4 waves, tile 128x128, BK=32.
// ---------------------------------------------------------------------------
__global__ __launch_bounds__(256) void gemm_bf16(const unsigned short* __restrict__ A,
                                                 const unsigned short* __restrict__ Bt,
                                                 void* __restrict__ Cv,
                                                 int M, int N, int K, int c_bf16) {
  __shared__ unsigned short As[128 * 32];
  __shared__ unsigned short Bs[128 * 32];
  const int tid = threadIdx.x;
  const int lane = tid & 63;
  const int wave = tid >> 6;
  const int wm = (wave >> 1) << 6;
  const int wn = (wave & 1) << 6;
  const int m0 = blockIdx.y * 128, n0 = blockIdx.x * 128;

  const int srow = tid >> 1;
  const int sg = (tid & 1) * 2;
  const size_t a_base = (size_t)(m0 + srow) * K + sg * 8;
  const size_t b_base = (size_t)(n0 + srow) * K + sg * 8;
  const int w0 = srow * 64 + ((sg ^ (srow & 3)) << 4);
  const int w1 = srow * 64 + (((sg + 1) ^ (srow & 3)) << 4);

  const int frow = lane & 15, fg = lane >> 4;
  int a_roff[4], b_roff[4];
#pragma unroll
  for (int m = 0; m < 4; ++m) {
    int r = wm + m * 16 + frow;
    a_roff[m] = r * 64 + ((fg ^ (r & 3)) << 4);
  }
#pragma unroll
  for (int n = 0; n < 4; ++n) {
    int r = wn + n * 16 + frow;
    b_roff[n] = r * 64 + ((fg ^ (r & 3)) << 4);
  }

  f32x4 acc[4][4];
#pragma unroll
  for (int m = 0; m < 4; ++m)
#pragma unroll
    for (int n = 0; n < 4; ++n) acc[m][n] = (f32x4){0.f, 0.f, 0.f, 0.f};

  for (int k0 = 0; k0 < K; k0 += 32) {
    uint4 va  = *(const uint4*)(A + a_base + k0);
    uint4 va2 = *(const uint4*)(A + a_base + k0 + 8);
    uint4 vb  = *(const uint4*)(Bt + b_base + k0);
    uint4 vb2 = *(const uint4*)(Bt + b_base + k0 + 8);
    __syncthreads();
    *(uint4*)((char*)As + w0) = va;
    *(uint4*)((char*)As + w1) = va2;
    *(uint4*)((char*)Bs + w0) = vb;
    *(uint4*)((char*)Bs + w1) = vb2;
    __syncthreads();
    short8 af[4], bfr[4];
#pragma unroll
    for (int m = 0; m < 4; ++m) af[m] = *(const short8*)((const char*)As + a_roff[m]);
#pragma unroll
    for (int n = 0; n < 4; ++n) bfr[n] = *(const short8*)((const char*)Bs + b_roff[n]);
#pragma unroll
    for (int m = 0; m < 4; ++m)
#pragma unroll
      for (int n = 0; n < 4; ++n)
        acc[m][n] = __builtin_amdgcn_mfma_f32_16x16x32_bf16(af[m], bfr[n], acc[m][n], 0, 0, 0);
  }

  const int crow = (lane >> 4) * 4;
  const int ccol = lane & 15;
  if (c_bf16) {
    unsigned short* Cb = (unsigned short*)Cv;
#pragma unroll
    for (int m = 0; m < 4; ++m)
#pragma unroll
      for (int n = 0; n < 4; ++n)
#pragma unroll
        for (int r = 0; r < 4; ++r)
          Cb[(size_t)(m0 + wm + m * 16 + crow + r) * N + n0 + wn + n * 16 + ccol] =
              f2bf(acc[m][n][r]);
  } else {
    float* Cf = (float*)Cv;
#pragma unroll
    for (int m = 0; m < 4; ++m)
#pragma unroll
      for (int n = 0; n < 4; ++n)
#pragma unroll
        for (int r = 0; r < 4; ++r)
          Cf[(size_t)(m0 + wm + m * 16 + crow + r) * N + n0 + wn + n * 16 + ccol] =
              acc[m][n][r];
  }
}

// ---------------------------------------------------------------------------
// In-place RMSNorm on bf16 buffer
// ---------------------------------------------------------------------------
__global__ __launch_bounds__(256) void rmsnorm_bf16(unsigned short* __restrict__ x,
                                                    const float* __restrict__ g,
                                                    int cols, float inv_cols) {
  const int row = blockIdx.x;
  unsigned short* p = x + (size_t)row * cols;
  float ss = 0.f;
  for (int c = threadIdx.x; c < cols; c += 256) { float v = bf2f(p[c]); ss += v * v; }
#pragma unroll
  for (int off = 32; off >= 1; off >>= 1) ss += __shfl_xor(ss, off, 64);
  __shared__ float wsum[4];
  if ((threadIdx.x & 63) == 0) wsum[threadIdx.x >> 6] = ss;
  __syncthreads();
  float tot = (wsum[0] + wsum[1]) + (wsum[2] + wsum[3]);
  float r = rsqrtf(tot * inv_cols + 1e-6f);
  for (int c = threadIdx.x; c < cols; c += 256) p[c] = f2bf(bf2f(p[c]) * r * g[c]);
}

// ---------------------------------------------------------------------------
// RoPE on bf16 q_rope [4096][512]. Reference's sin table == cos table.
// ---------------------------------------------------------------------------
__global__ __launch_bounds__(256) void rope_q_bf16(unsigned short* __restrict__ qr) {
  const int row = blockIdx.x;
  const int t = threadIdx.x;
  const int h = t >> 4, i = t & 15;
  const int pos = row & (S_ - 1);
  float freq = powf(10000.0f, -(float)i / 16.0f);
  float c = cosf((float)pos * freq);
  unsigned* p = (unsigned*)(qr + (size_t)row * 512 + h * 32 + 2 * i);
  unsigned v = *p;
  float xr = bf2f((unsigned short)(v & 0xffffu));
  float xi = bf2f((unsigned short)(v >> 16));
  unsigned short o0 = f2bf((xr - xi) * c);
  unsigned short o1 = f2bf((xr + xi) * c);
  *p = (unsigned)o0 | ((unsigned)o1 << 16);
}

// ---------------------------------------------------------------------------
// k_rope as MFMA GEMM + fused rope epilogue
// ---------------------------------------------------------------------------
__global__ __launch_bounds__(256) void gemm_kr_rope(
    const unsigned short* __restrict__ xb,   // [4096][2048]
    const unsigned short* __restrict__ wkrT, // [32][2048]
    unsigned short* __restrict__ krb) {      // [4096][32]
  __shared__ unsigned short As[64 * 64];
  __shared__ unsigned short Bs[32 * 64];
  const int tid = threadIdx.x;
  const int lane = tid & 63;
  const int wave = tid >> 6;
  const int m0 = blockIdx.x * 64;
  const int frow = lane & 15, fg = lane >> 4;

  const int arow = tid >> 2;
  const int ag = (tid & 3) * 2;
  const int brow = tid >> 3;
  const int bg = tid & 7;

  f32x4 acc[2];
  acc[0] = (f32x4){0.f, 0.f, 0.f, 0.f};
  acc[1] = (f32x4){0.f, 0.f, 0.f, 0.f};

  for (int k0 = 0; k0 < 2048; k0 += 64) {
    uint4 va0 = *(const uint4*)&xb[(size_t)(m0 + arow) * 2048 + k0 + ag * 8];
    uint4 va1 = *(const uint4*)&xb[(size_t)(m0 + arow) * 2048 + k0 + ag * 8 + 8];
    uint4 vb  = *(const uint4*)&wkrT[(size_t)brow * 2048 + k0 + bg * 8];
    __syncthreads();
    *(uint4*)((char*)As + arow * 128 + ((ag ^ (arow & 7)) << 4))       = va0;
    *(uint4*)((char*)As + arow * 128 + (((ag + 1) ^ (arow & 7)) << 4)) = va1;
    *(uint4*)((char*)Bs + brow * 128 + ((bg ^ (brow & 7)) << 4))       = vb;
    __syncthreads();
#pragma unroll
    for (int kk = 0; kk < 2; ++kk) {
      const int ar = wave * 16 + frow;
      short8 aq = *(const short8*)((const char*)As + ar * 128 + (((kk * 4 + fg) ^ (ar & 7)) << 4));
#pragma unroll
      for (int n = 0; n < 2; ++n) {
        const int br = n * 16 + frow;
        short8 bk = *(const short8*)((const char*)Bs + br * 128 + (((kk * 4 + fg) ^ (br & 7)) << 4));
        acc[n] = __builtin_amdgcn_mfma_f32_16x16x32_bf16(aq, bk, acc[n], 0, 0, 0);
      }
    }
  }
  const int ccol = lane & 15, crow = (lane >> 4) * 4;
#pragma unroll
  for (int n = 0; n < 2; ++n) {
    const int col = n * 16 + ccol;
    const int i = col >> 1;
    const float freq = powf(10000.0f, -(float)i / 16.0f);
#pragma unroll
    for (int r = 0; r < 4; ++r) {
      const int row = m0 + wave * 16 + crow + r;
      float v = acc[n][r] * (1.0f / 16.0f);
      float other = __shfl_xor(v, 1, 64);
      float c = cosf((float)(row & (S_ - 1)) * freq);
      float outv = (col & 1) ? (other + v) * c : (v - other) * c;
      krb[(size_t)row * 32 + col] = f2bf(outv);
    }
  }
}

// ---------------------------------------------------------------------------
// MFMA flash attention, swapped-operand layout (softmax lane-local).
// 256 thr = 4 waves; q-tile 64 rows (wave w owns rows w*16..w*16+15);
// k-tiles of 64. Grid x: 32 q-tiles in LPT order (largest first).
// QK^T computed as mfma(K_frag, Q_frag) -> lane holds S[q=lane&15][k=fg*4+r]
//   (16 k-slots of ONE q-row per lane) -> row reduce = in-lane + 2 shfl.
// PV computed as mfma(V_frag, P_frag) -> lane holds O[q=lane&15][d=fg*4+r],
//   so m/l/rescale stay lane-local end-to-end.
// P packed to bf16 via v_cvt_pk_bf16_f32, written as ds_write_b64.
// ---------------------------------------------------------------------------
#define QK_STRIDE 104   // 96 data + pad; 208B row
#define PV_STRIDE 72    // 64 data + pad; 144B row

__global__ __launch_bounds__(256) void attn_mfma(
    const unsigned short* __restrict__ qnb,  // [4096][1024]
    const unsigned short* __restrict__ qrb,  // [4096][512]
    const unsigned short* __restrict__ knb,  // [4096][1024]
    const unsigned short* __restrict__ krb,  // [4096][32]
    const unsigned short* __restrict__ vvT,  // [1024][4096]: [h*64+d][b*2048+s]
    unsigned short* __restrict__ aob) {      // [4096][1024]
  __shared__ unsigned short Qs[64 * QK_STRIDE];
  __shared__ unsigned short Ks[64 * QK_STRIDE];
  __shared__ unsigned short Vt[64 * PV_STRIDE];
  __shared__ unsigned short Ps[64 * PV_STRIDE];
  const int tid = threadIdx.x;
  const int lane = tid & 63;
  const int wave = tid >> 6;
  const int bh = blockIdx.y;
  const int b = bh >> 4, h = bh & 15;
  const size_t rowbase = (size_t)b * S_;
  const int frow = lane & 15, fg = lane >> 4;
  const int ccol = lane & 15;          // this lane's q-row within the wave
  const int crow = fg * 4;             // this lane's k/d sub-slot base
  const float C2 = 0.10206207261596575f * 1.4426950408889634f;  // scale*log2(e)

  const int q0 = (31 - blockIdx.x) * 64;   // LPT: largest q-tile first

  {  // load Q tile: nope 64 + rope 32 bf16 per row
    int g = tid;
#pragma unroll
    for (int rep = 0; rep < 2; ++rep, g += 256) {
      int row = g >> 3, col = (g & 7) * 8;
      *(uint4*)&Qs[row * QK_STRIDE + col] =
          *(const uint4*)&qnb[(size_t)(rowbase + q0 + row) * 1024 + (h << 6) + col];
    }
    int row = tid >> 2, col = (tid & 3) * 8;
    *(uint4*)&Qs[row * QK_STRIDE + 64 + col] =
        *(const uint4*)&qrb[(size_t)(rowbase + q0 + row) * 512 + (h << 5) + col];
  }

  float m = -1e30f, l = 0.f;           // per-lane: one q-row
  f32x4 acc_o[4];
#pragma unroll
  for (int n = 0; n < 4; ++n) acc_o[n] = (f32x4){0.f, 0.f, 0.f, 0.f};

  for (int k0 = 0; k0 <= q0; k0 += 64) {
    __syncthreads();  // prev iter's Ks/Vt reads (and Qs writes on iter 0) done
    {  // load K tile + Vt tile
      int g = tid;
#pragma unroll
      for (int rep = 0; rep < 2; ++rep, g += 256) {
        int row = g >> 3, col = (g & 7) * 8;
        *(uint4*)&Ks[row * QK_STRIDE + col] =
            *(const uint4*)&knb[(size_t)(rowbase + k0 + row) * 1024 + (h << 6) + col];
        *(uint4*)&Vt[row * PV_STRIDE + col] =
            *(const uint4*)&vvT[(size_t)((h << 6) + row) * 4096 + b * S_ + k0 + col];
      }
      int row = tid >> 2, col = (tid & 3) * 8;
      *(uint4*)&Ks[row * QK_STRIDE + 64 + col] =
          *(const uint4*)&krb[(size_t)(rowbase + k0 + row) * 32 + col];
    }
    __syncthreads();

    // ---- QK^T (swapped: A=K, B=Q) -> S[q=ccol][k=n*16+crow+r] ----
    f32x4 sa[4];
#pragma unroll
    for (int n = 0; n < 4; ++n) sa[n] = (f32x4){0.f, 0.f, 0.f, 0.f};
#pragma unroll
    for (int c = 0; c < 3; ++c) {
      short8 aq = *(const short8*)&Qs[(wave * 16 + frow) * QK_STRIDE + c * 32 + fg * 8];
#pragma unroll
      for (int n = 0; n < 4; ++n) {
        short8 bk = *(const short8*)&Ks[(n * 16 + frow) * QK_STRIDE + c * 32 + fg * 8];
        sa[n] = __builtin_amdgcn_mfma_f32_16x16x32_bf16(bk, aq, sa[n], 0, 0, 0);
      }
    }
    if (k0 == q0) {  // diagonal tile: mask k > q (within-tile indices)
      const int qloc = wave * 16 + ccol;
#pragma unroll
      for (int n = 0; n < 4; ++n)
#pragma unroll
        for (int r = 0; r < 4; ++r)
          if (n * 16 + crow + r > qloc) sa[n][r] = -1e30f;
    }

    // ---- online softmax: in-lane over 16 + 2 shfl across fg-duplicates ----
    float mx = sa[0][0];
#pragma unroll
    for (int n = 0; n < 4; ++n)
#pragma unroll
      for (int r = 0; r < 4; ++r) mx = fmaxf(mx, sa[n][r]);
    mx = fmaxf(mx, __shfl_xor(mx, 16, 64));
    mx = fmaxf(mx, __shfl_xor(mx, 32, 64));

    if (!__all(mx <= m)) {
      float mn = fmaxf(m, mx);
      float ra = exp2f((m - mn) * C2);
      m = mn;
      l *= ra;
#pragma unroll
      for (int n = 0; n < 4; ++n) {
        acc_o[n][0] *= ra; acc_o[n][1] *= ra;
        acc_o[n][2] *= ra; acc_o[n][3] *= ra;
      }
    }
    const float mC2 = m * C2;
    float p[4][4];
    float rs = 0.f;
#pragma unroll
    for (int n = 0; n < 4; ++n)
#pragma unroll
      for (int r = 0; r < 4; ++r) {
        p[n][r] = exp2f(fmaf(sa[n][r], C2, -mC2));
        rs += p[n][r];
      }
    rs += __shfl_xor(rs, 16, 64);
    rs += __shfl_xor(rs, 32, 64);
    l += rs;

    // ---- P -> LDS: row = q (wave*16+ccol), packed 4 bf16 per b64 ----
#pragma unroll
    for (int n = 0; n < 4; ++n) {
      uint2v pk;
      pk.x = cvtpk_bf16(p[n][0], p[n][1]);
      pk.y = cvtpk_bf16(p[n][2], p[n][3]);
      *(uint2v*)&Ps[(wave * 16 + ccol) * PV_STRIDE + n * 16 + crow] = pk;
    }
    __builtin_amdgcn_wave_barrier();

    // ---- PV (swapped: A=V^T, B=P) -> O[q=ccol][d=n*16+crow+r] ----
#pragma unroll
    for (int c = 0; c < 2; ++c) {
      short8 ap = *(const short8*)&Ps[(wave * 16 + frow) * PV_STRIDE + c * 32 + fg * 8];
#pragma unroll
      for (int n = 0; n < 4; ++n) {
        short8 bv = *(const short8*)&Vt[(n * 16 + frow) * PV_STRIDE + c * 32 + fg * 8];
        acc_o[n] = __builtin_amdgcn_mfma_f32_16x16x32_bf16(bv, ap, acc_o[n], 0, 0, 0);
      }
    }
    __builtin_amdgcn_wave_barrier();
  }

  // ---- epilogue: lane owns q-row (q0+wave*16+ccol), d = n*16+crow+r ----
  const float inv = 1.f / l;
  const size_t obase = (size_t)(rowbase + q0 + wave * 16 + ccol) * 1024 + (h << 6);
#pragma unroll
  for (int n = 0; n < 4; ++n) {
    uint2v pk;
    pk.x = cvtpk_bf16(acc_o[n][0] * inv, acc_o[n][1] * inv);
    pk.y = cvtpk_bf16(acc_o[n][2] * inv, acc_o[n][3] * inv);
    *(uint2v*)&aob[obase + n * 16 + crow] = pk;
  }
}

// ---------------------------------------------------------------------------
extern "C" void kernel_launch(void* const* d_in, const int* in_sizes, int n_in,
                              void* d_out, int out_size, void* d_ws, size_t ws_size,
                              hipStream_t stream) {
  const float* x        = (const float*)d_in[0];
  const float* w_cq     = (const float*)d_in[1];
  const float* w_q_nope = (const float*)d_in[2];
  const float* w_q_rope = (const float*)d_in[3];
  const float* q_g      = (const float*)d_in[4];
  const float* w_ckv    = (const float*)d_in[5];
  const float* w_k_nope = (const float*)d_in[6];
  const float* w_v      = (const float*)d_in[7];
  const float* kv_g     = (const float*)d_in[8];
  const float* w_k_rope = (const float*)d_in[9];
  const float* w_proj   = (const float*)d_in[10];
  float* out = (float*)d_out;

  // ---- workspace layout (bf16) ----
  char* w = (char*)d_ws;
  unsigned short* xb    = (unsigned short*)w; w += (size_t)ROWS * 2048 * 2;
  unsigned short* cqb   = (unsigned short*)w; w += (size_t)ROWS * QRANK * 2;
  unsigned short* ckvb  = (unsigned short*)w; w += (size_t)ROWS * KVRANK * 2;
  unsigned short* qnb   = (unsigned short*)w; w += (size_t)ROWS * 1024 * 2;
  unsigned short* qrb   = (unsigned short*)w; w += (size_t)ROWS * 512 * 2;
  unsigned short* knb   = (unsigned short*)w; w += (size_t)ROWS * 1024 * 2;
  unsigned short* vvb   = (unsigned short*)w; w += (size_t)ROWS * 1024 * 2;
  unsigned short* vvT   = (unsigned short*)w; w += (size_t)1024 * ROWS * 2;
  unsigned short* krb   = (unsigned short*)w; w += (size_t)ROWS * 32 * 2;
  unsigned short* aob   = (unsigned short*)w; w += (size_t)ROWS * 1024 * 2;
  unsigned short* wcqT  = (unsigned short*)w; w += (size_t)QRANK * 2048 * 2;
  unsigned short* wqnT  = (unsigned short*)w; w += (size_t)1024 * QRANK * 2;
  unsigned short* wqrT  = (unsigned short*)w; w += (size_t)512 * QRANK * 2;
  unsigned short* wckvT = (unsigned short*)w; w += (size_t)KVRANK * 2048 * 2;
  unsigned short* wknT  = (unsigned short*)w; w += (size_t)1024 * KVRANK * 2;
  unsigned short* wvT   = (unsigned short*)w; w += (size_t)1024 * KVRANK * 2;
  unsigned short* wprojT= (unsigned short*)w; w += (size_t)2048 * 1024 * 2;
  unsigned short* wkrT  = (unsigned short*)w; w += (size_t)32 * 2048 * 2;

  // ---- casts & weight transposes ----
  cast_to_bf16<<<ROWS * 2048 / (256 * 8), 256, 0, stream>>>(x, xb, ROWS * 2048);
  transpose_cast<<<dim3(QRANK / 32, 2048 / 32), 256, 0, stream>>>(w_cq, wcqT, 2048, QRANK);
  transpose_cast<<<dim3(1024 / 32, QRANK / 32), 256, 0, stream>>>(w_q_nope, wqnT, QRANK, 1024);
  transpose_cast<<<dim3(512 / 32, QRANK / 32), 256, 0, stream>>>(w_q_rope, wqrT, QRANK, 512);
  transpose_cast<<<dim3(KVRANK / 32, 2048 / 32), 256, 0, stream>>>(w_ckv, wckvT, 2048, KVRANK);
  transpose_cast<<<dim3(1024 / 32, KVRANK / 32), 256, 0, stream>>>(w_k_nope, wknT, KVRANK, 1024);
  transpose_cast<<<dim3(1024 / 32, KVRANK / 32), 256, 0, stream>>>(w_v, wvT, KVRANK, 1024);
  transpose_cast<<<dim3(2048 / 32, 1024 / 32), 256, 0, stream>>>(w_proj, wprojT, 1024, 2048);
  transpose_cast<<<dim3(32 / 32, 2048 / 32), 256, 0, stream>>>(w_k_rope, wkrT, 2048, 32);

  // ---- projections (bf16 MFMA, bf16 outputs) ----
  gemm_bf16<<<dim3(QRANK / 128, ROWS / 128), 256, 0, stream>>>(xb, wcqT, cqb, ROWS, QRANK, 2048, 1);
  rmsnorm_bf16<<<ROWS, 256, 0, stream>>>(cqb, q_g, QRANK, 1.0f / QRANK);
  gemm_bf16<<<dim3(1024 / 128, ROWS / 128), 256, 0, stream>>>(cqb, wqnT, qnb, ROWS, 1024, QRANK, 1);
  gemm_bf16<<<dim3(512 / 128, ROWS / 128), 256, 0, stream>>>(cqb, wqrT, qrb, ROWS, 512, QRANK, 1);
  rope_q_bf16<<<ROWS, 256, 0, stream>>>(qrb);
  gemm_bf16<<<dim3(KVRANK / 128, ROWS / 128), 256, 0, stream>>>(xb, wckvT, ckvb, ROWS, KVRANK, 2048, 1);
  rmsnorm_bf16<<<ROWS, 256, 0, stream>>>(ckvb, kv_g, KVRANK, 1.0f / KVRANK);
  gemm_bf16<<<dim3(1024 / 128, ROWS / 128), 256, 0, stream>>>(ckvb, wknT, knb, ROWS, 1024, KVRANK, 1);
  gemm_bf16<<<dim3(1024 / 128, ROWS / 128), 256, 0, stream>>>(ckvb, wvT, vvb, ROWS, 1024, KVRANK, 1);
  transpose_bf16<<<dim3(1024 / 32, ROWS / 32), 256, 0, stream>>>(vvb, vvT, ROWS, 1024);
  gemm_kr_rope<<<ROWS / 64, 256, 0, stream>>>(xb, wkrT, krb);

  // ---- attention (MFMA flash, swapped-operand) ----
  attn_mfma<<<dim3(32, 32), 256, 0, stream>>>(qnb, qrb, knb, krb, vvT, aob);

  // ---- output projection ----
  gemm_bf16<<<dim3(2048 / 128, ROWS / 128), 256, 0, stream>>>(aob, wprojT, out, ROWS, 2048, 1024, 0);
}

// Round 7
// 336.351 us; speedup vs baseline: 1.1402x; 1.1402x over previous
//
#include <hip/hip_runtime.h>
#include <hip/hip_bf16.h>
#include <math.h>

#define B_      2
#define S_      2048
#define D_      2048
#define H_      16
#define NOPE_D  64
#define ROPE_DD 32
#define V_DD    64
#define QRANK   768
#define KVRANK  256
#define ROWS    (B_ * S_)   // 4096

typedef __attribute__((ext_vector_type(8))) short short8;
typedef __attribute__((ext_vector_type(4))) float f32x4;
typedef __attribute__((ext_vector_type(4))) unsigned short ushort4v;
typedef __attribute__((ext_vector_type(2))) unsigned int uint2v;

__device__ __forceinline__ float bf2f(unsigned short u) {
  return __uint_as_float(((unsigned)u) << 16);
}
__device__ __forceinline__ unsigned short f2bf(float f) {  // RNE
  unsigned u = __float_as_uint(f);
  return (unsigned short)((u + 0x7fffu + ((u >> 16) & 1u)) >> 16);
}
__device__ __forceinline__ unsigned cvtpk_bf16(float lo, float hi) {
  unsigned r;
  asm("v_cvt_pk_bf16_f32 %0, %1, %2" : "=v"(r) : "v"(lo), "v"(hi));
  return r;
}

// ---------------------------------------------------------------------------
// cast fp32 -> bf16, 8 elems/thread
// ---------------------------------------------------------------------------
__global__ __launch_bounds__(256) void cast_to_bf16(const float* __restrict__ in,
                                                    unsigned short* __restrict__ out,
                                                    int n) {
  int i = (blockIdx.x * 256 + threadIdx.x) * 8;
  if (i >= n) return;
  float4 a = *(const float4*)(in + i);
  float4 b = *(const float4*)(in + i + 4);
  unsigned short r[8] = {f2bf(a.x), f2bf(a.y), f2bf(a.z), f2bf(a.w),
                         f2bf(b.x), f2bf(b.y), f2bf(b.z), f2bf(b.w)};
  *(ushort4v*)(out + i)     = *(ushort4v*)&r[0];
  *(ushort4v*)(out + i + 4) = *(ushort4v*)&r[4];
}

// ---------------------------------------------------------------------------
// transpose + cast: in [R][C] fp32 -> out [C][R] bf16.  R,C % 32 == 0.
// ---------------------------------------------------------------------------
__global__ __launch_bounds__(256) void transpose_cast(const float* __restrict__ in,
                                                      unsigned short* __restrict__ out,
                                                      int R, int C) {
  __shared__ unsigned short t[32][33];
  const int c0 = blockIdx.x * 32, r0 = blockIdx.y * 32;
  const int tx = threadIdx.x & 31, ty = threadIdx.x >> 5;  // ty 0..7
#pragma unroll
  for (int i = 0; i < 32; i += 8)
    t[ty + i][tx] = f2bf(in[(size_t)(r0 + ty + i) * C + c0 + tx]);
  __syncthreads();
#pragma unroll
  for (int i = 0; i < 32; i += 8)
    out[(size_t)(c0 + ty + i) * R + r0 + tx] = t[tx][ty + i];
}

// ---------------------------------------------------------------------------
// transpose bf16: in [R][C] -> out [C][R]
// ---------------------------------------------------------------------------
__global__ __launch_bounds__(256) void transpose_bf16(const unsigned short* __restrict__ in,
                                                      unsigned short* __restrict__ out,
                                                      int R, int C) {
  __shared__ unsigned short t[32][33];
  const int c0 = blockIdx.x * 32, r0 = blockIdx.y * 32;
  const int tx = threadIdx.x & 31, ty = threadIdx.x >> 5;
#pragma unroll
  for (int i = 0; i < 32; i += 8)
    t[ty + i][tx] = in[(size_t)(r0 + ty + i) * C + c0 + tx];
  __syncthreads();
#pragma unroll
  for (int i = 0; i < 32; i += 8)
    out[(size_t)(c0 + ty + i) * R + r0 + tx] = t[tx][ty + i];
}

// ---------------------------------------------------------------------------
// bf16 MFMA GEMM (TN): A [M][K] bf16, Bt [N][K] bf16, C [M][N] (f32 or bf16).
// M%128==0, N%128==0, K%32==0. 256 thr = 4 waves, tile 128x128, BK=32.
// ---------------------------------------------------------------------------
__global__ __launch_bounds__(256) void gemm_bf16(const unsigned short* __restrict__ A,
                                                 const unsigned short* __restrict__ Bt,
                                                 void* __restrict__ Cv,
                                                 int M, int N, int K, int c_bf16) {
  __shared__ unsigned short As[128 * 32];
  __shared__ unsigned short Bs[128 * 32];
  const int tid = threadIdx.x;
  const int lane = tid & 63;
  const int wave = tid >> 6;
  const int wm = (wave >> 1) << 6;
  const int wn = (wave & 1) << 6;
  const int m0 = blockIdx.y * 128, n0 = blockIdx.x * 128;

  const int srow = tid >> 1;
  const int sg = (tid & 1) * 2;
  const size_t a_base = (size_t)(m0 + srow) * K + sg * 8;
  const size_t b_base = (size_t)(n0 + srow) * K + sg * 8;
  const int w0 = srow * 64 + ((sg ^ (srow & 3)) << 4);
  const int w1 = srow * 64 + (((sg + 1) ^ (srow & 3)) << 4);

  const int frow = lane & 15, fg = lane >> 4;
  int a_roff[4], b_roff[4];
#pragma unroll
  for (int m = 0; m < 4; ++m) {
    int r = wm + m * 16 + frow;
    a_roff[m] = r * 64 + ((fg ^ (r & 3)) << 4);
  }
#pragma unroll
  for (int n = 0; n < 4; ++n) {
    int r = wn + n * 16 + frow;
    b_roff[n] = r * 64 + ((fg ^ (r & 3)) << 4);
  }

  f32x4 acc[4][4];
#pragma unroll
  for (int m = 0; m < 4; ++m)
#pragma unroll
    for (int n = 0; n < 4; ++n) acc[m][n] = (f32x4){0.f, 0.f, 0.f, 0.f};

  for (int k0 = 0; k0 < K; k0 += 32) {
    uint4 va  = *(const uint4*)(A + a_base + k0);
    uint4 va2 = *(const uint4*)(A + a_base + k0 + 8);
    uint4 vb  = *(const uint4*)(Bt + b_base + k0);
    uint4 vb2 = *(const uint4*)(Bt + b_base + k0 + 8);
    __syncthreads();
    *(uint4*)((char*)As + w0) = va;
    *(uint4*)((char*)As + w1) = va2;
    *(uint4*)((char*)Bs + w0) = vb;
    *(uint4*)((char*)Bs + w1) = vb2;
    __syncthreads();
    short8 af[4], bfr[4];
#pragma unroll
    for (int m = 0; m < 4; ++m) af[m] = *(const short8*)((const char*)As + a_roff[m]);
#pragma unroll
    for (int n = 0; n < 4; ++n) bfr[n] = *(const short8*)((const char*)Bs + b_roff[n]);
#pragma unroll
    for (int m = 0; m < 4; ++m)
#pragma unroll
      for (int n = 0; n < 4; ++n)
        acc[m][n] = __builtin_amdgcn_mfma_f32_16x16x32_bf16(af[m], bfr[n], acc[m][n], 0, 0, 0);
  }

  const int crow = (lane >> 4) * 4;
  const int ccol = lane & 15;
  if (c_bf16) {
    unsigned short* Cb = (unsigned short*)Cv;
#pragma unroll
    for (int m = 0; m < 4; ++m)
#pragma unroll
      for (int n = 0; n < 4; ++n)
#pragma unroll
        for (int r = 0; r < 4; ++r)
          Cb[(size_t)(m0 + wm + m * 16 + crow + r) * N + n0 + wn + n * 16 + ccol] =
              f2bf(acc[m][n][r]);
  } else {
    float* Cf = (float*)Cv;
#pragma unroll
    for (int m = 0; m < 4; ++m)
#pragma unroll
      for (int n = 0; n < 4; ++n)
#pragma unroll
        for (int r = 0; r < 4; ++r)
          Cf[(size_t)(m0 + wm + m * 16 + crow + r) * N + n0 + wn + n * 16 + ccol] =
              acc[m][n][r];
  }
}

// ---------------------------------------------------------------------------
// In-place RMSNorm on bf16 buffer
// ---------------------------------------------------------------------------
__global__ __launch_bounds__(256) void rmsnorm_bf16(unsigned short* __restrict__ x,
                                                    const float* __restrict__ g,
                                                    int cols, float inv_cols) {
  const int row = blockIdx.x;
  unsigned short* p = x + (size_t)row * cols;
  float ss = 0.f;
  for (int c = threadIdx.x; c < cols; c += 256) { float v = bf2f(p[c]); ss += v * v; }
#pragma unroll
  for (int off = 32; off >= 1; off >>= 1) ss += __shfl_xor(ss, off, 64);
  __shared__ float wsum[4];
  if ((threadIdx.x & 63) == 0) wsum[threadIdx.x >> 6] = ss;
  __syncthreads();
  float tot = (wsum[0] + wsum[1]) + (wsum[2] + wsum[3]);
  float r = rsqrtf(tot * inv_cols + 1e-6f);
  for (int c = threadIdx.x; c < cols; c += 256) p[c] = f2bf(bf2f(p[c]) * r * g[c]);
}

// ---------------------------------------------------------------------------
// RoPE on bf16 q_rope [4096][512]. Reference's sin table == cos table.
// freq = 10000^(-i/16) = exp2(-i * log2(1e4)/16)
// ---------------------------------------------------------------------------
__global__ __launch_bounds__(256) void rope_q_bf16(unsigned short* __restrict__ qr) {
  const int row = blockIdx.x;
  const int t = threadIdx.x;
  const int h = t >> 4, i = t & 15;
  const int pos = row & (S_ - 1);
  float freq = exp2f(-0.8304820237218406f * (float)i);
  float c = cosf((float)pos * freq);
  unsigned* p = (unsigned*)(qr + (size_t)row * 512 + h * 32 + 2 * i);
  unsigned v = *p;
  float xr = bf2f((unsigned short)(v & 0xffffu));
  float xi = bf2f((unsigned short)(v >> 16));
  unsigned short o0 = f2bf((xr - xi) * c);
  unsigned short o1 = f2bf((xr + xi) * c);
  *p = (unsigned)o0 | ((unsigned)o1 << 16);
}

// ---------------------------------------------------------------------------
// k_rope as MFMA GEMM + fused rope epilogue
// ---------------------------------------------------------------------------
__global__ __launch_bounds__(256) void gemm_kr_rope(
    const unsigned short* __restrict__ xb,   // [4096][2048]
    const unsigned short* __restrict__ wkrT, // [32][2048]
    unsigned short* __restrict__ krb) {      // [4096][32]
  __shared__ unsigned short As[64 * 64];
  __shared__ unsigned short Bs[32 * 64];
  const int tid = threadIdx.x;
  const int lane = tid & 63;
  const int wave = tid >> 6;
  const int m0 = blockIdx.x * 64;
  const int frow = lane & 15, fg = lane >> 4;

  const int arow = tid >> 2;
  const int ag = (tid & 3) * 2;
  const int brow = tid >> 3;
  const int bg = tid & 7;

  f32x4 acc[2];
  acc[0] = (f32x4){0.f, 0.f, 0.f, 0.f};
  acc[1] = (f32x4){0.f, 0.f, 0.f, 0.f};

  for (int k0 = 0; k0 < 2048; k0 += 64) {
    uint4 va0 = *(const uint4*)&xb[(size_t)(m0 + arow) * 2048 + k0 + ag * 8];
    uint4 va1 = *(const uint4*)&xb[(size_t)(m0 + arow) * 2048 + k0 + ag * 8 + 8];
    uint4 vb  = *(const uint4*)&wkrT[(size_t)brow * 2048 + k0 + bg * 8];
    __syncthreads();
    *(uint4*)((char*)As + arow * 128 + ((ag ^ (arow & 7)) << 4))       = va0;
    *(uint4*)((char*)As + arow * 128 + (((ag + 1) ^ (arow & 7)) << 4)) = va1;
    *(uint4*)((char*)Bs + brow * 128 + ((bg ^ (brow & 7)) << 4))       = vb;
    __syncthreads();
#pragma unroll
    for (int kk = 0; kk < 2; ++kk) {
      const int ar = wave * 16 + frow;
      short8 aq = *(const short8*)((const char*)As + ar * 128 + (((kk * 4 + fg) ^ (ar & 7)) << 4));
#pragma unroll
      for (int n = 0; n < 2; ++n) {
        const int br = n * 16 + frow;
        short8 bk = *(const short8*)((const char*)Bs + br * 128 + (((kk * 4 + fg) ^ (br & 7)) << 4));
        acc[n] = __builtin_amdgcn_mfma_f32_16x16x32_bf16(aq, bk, acc[n], 0, 0, 0);
      }
    }
  }
  const int ccol = lane & 15, crow = (lane >> 4) * 4;
#pragma unroll
  for (int n = 0; n < 2; ++n) {
    const int col = n * 16 + ccol;
    const int i = col >> 1;
    const float freq = exp2f(-0.8304820237218406f * (float)i);
#pragma unroll
    for (int r = 0; r < 4; ++r) {
      const int row = m0 + wave * 16 + crow + r;
      float v = acc[n][r] * (1.0f / 16.0f);
      float other = __shfl_xor(v, 1, 64);
      float c = cosf((float)(row & (S_ - 1)) * freq);
      float outv = (col & 1) ? (other + v) * c : (v - other) * c;
      krb[(size_t)row * 32 + col] = f2bf(outv);
    }
  }
}

// ---------------------------------------------------------------------------
// MFMA flash attention, dual-tile 8-wave blocks, lane-local softmax.
// Grid (16, 32): block p owns q-tiles {p, 31-p}; waves 0-3 compute tile p,
// waves 4-7 compute tile 31-p CONCURRENTLY, sharing the K/V staging loop
// (32-p iters; small tile masks off once past its diagonal).
// Q fragments live in registers (loaded once from global; no Q LDS).
// QK^T as mfma(K,Q) -> lane holds S[q=lane&15][16 k-slots] -> in-lane reduce.
// PV as mfma(V^T,P) -> O stays lane-local; P via cvt_pk + ds_write_b64.
// ---------------------------------------------------------------------------
#define QK_STRIDE 104   // 96 data + pad; 208B row
#define PV_STRIDE 72    // 64 data + pad; 144B row

__global__ __launch_bounds__(512, 4) void attn_mfma(
    const unsigned short* __restrict__ qnb,  // [4096][1024]
    const unsigned short* __restrict__ qrb,  // [4096][512]
    const unsigned short* __restrict__ knb,  // [4096][1024]
    const unsigned short* __restrict__ krb,  // [4096][32]
    const unsigned short* __restrict__ vvT,  // [1024][4096]: [h*64+d][b*2048+s]
    unsigned short* __restrict__ aob) {      // [4096][1024]
  __shared__ unsigned short Ks[64 * QK_STRIDE];   // 13.0 KB
  __shared__ unsigned short Vt[64 * PV_STRIDE];   //  9.0 KB
  __shared__ unsigned short Ps[128 * PV_STRIDE];  // 18.0 KB (64 rows per group)
  const int tid = threadIdx.x;
  const int lane = tid & 63;
  const int wave = tid >> 6;          // 0..7
  const int grp = wave >> 2;          // 0: tile p, 1: tile 31-p
  const int qw = wave & 3;
  const int p = blockIdx.x;           // 0..15
  const int bh = blockIdx.y;
  const int b = bh >> 4, h = bh & 15;
  const size_t rowbase = (size_t)b * S_;
  const int frow = lane & 15, fg = lane >> 4;
  const int ccol = frow;              // this lane's q-row within its wave
  const int crow = fg * 4;            // this lane's k/d sub-slot base
  const float C2 = 0.10206207261596575f * 1.4426950408889634f;  // scale*log2(e)

  const int q0 = (grp ? (31 - p) : p) * 64;
  const int nkt = 32 - p;             // staged k-tiles (covers the larger tile)

  // ---- Q fragments in registers (one q-row per lane, 96 dims) ----
  const size_t qrow = rowbase + q0 + qw * 16 + frow;
  short8 qf0 = *(const short8*)&qnb[qrow * 1024 + (h << 6) + fg * 8];
  short8 qf1 = *(const short8*)&qnb[qrow * 1024 + (h << 6) + 32 + fg * 8];
  short8 qf2 = *(const short8*)&qrb[qrow * 512 + (h << 5) + fg * 8];

  float m = -1e30f, l = 0.f;
  f32x4 acc_o[4];
#pragma unroll
  for (int n = 0; n < 4; ++n) acc_o[n] = (f32x4){0.f, 0.f, 0.f, 0.f};

  for (int kt = 0; kt < nkt; ++kt) {
    const int k0 = kt << 6;
    __syncthreads();  // prior iteration's Ks/Vt reads complete
    {  // staging: 512 threads, one uint4 each for K-nope and Vt
      const int row = tid >> 3, col = (tid & 7) * 8;
      *(uint4*)&Ks[row * QK_STRIDE + col] =
          *(const uint4*)&knb[(size_t)(rowbase + k0 + row) * 1024 + (h << 6) + col];
      *(uint4*)&Vt[row * PV_STRIDE + col] =
          *(const uint4*)&vvT[(size_t)((h << 6) + row) * 4096 + b * S_ + k0 + col];
      if (tid < 256) {
        const int rr = tid >> 2, rc = (tid & 3) * 8;
        *(uint4*)&Ks[rr * QK_STRIDE + 64 + rc] =
            *(const uint4*)&krb[(size_t)(rowbase + k0 + rr) * 32 + rc];
      }
    }
    __syncthreads();

    if (k0 <= q0) {
      // ---- QK^T (A=K, B=Q-regs) -> S[q=ccol][k=n*16+crow+r] ----
      f32x4 sa[4];
#pragma unroll
      for (int n = 0; n < 4; ++n) sa[n] = (f32x4){0.f, 0.f, 0.f, 0.f};
      __builtin_amdgcn_s_setprio(1);
#pragma unroll
      for (int n = 0; n < 4; ++n) {
        short8 bk0 = *(const short8*)&Ks[(n * 16 + frow) * QK_STRIDE + fg * 8];
        short8 bk1 = *(const short8*)&Ks[(n * 16 + frow) * QK_STRIDE + 32 + fg * 8];
        short8 bk2 = *(const short8*)&Ks[(n * 16 + frow) * QK_STRIDE + 64 + fg * 8];
        sa[n] = __builtin_amdgcn_mfma_f32_16x16x32_bf16(bk0, qf0, sa[n], 0, 0, 0);
        sa[n] = __builtin_amdgcn_mfma_f32_16x16x32_bf16(bk1, qf1, sa[n], 0, 0, 0);
        sa[n] = __builtin_amdgcn_mfma_f32_16x16x32_bf16(bk2, qf2, sa[n], 0, 0, 0);
      }
      __builtin_amdgcn_s_setprio(0);
      if (k0 == q0) {  // diagonal tile: mask k > q
        const int qloc = qw * 16 + ccol;
#pragma unroll
        for (int n = 0; n < 4; ++n)
#pragma unroll
          for (int r = 0; r < 4; ++r)
            if (n * 16 + crow + r > qloc) sa[n][r] = -1e30f;
      }

      // ---- online softmax: in-lane over 16 + 2 shfl ----
      float mx = sa[0][0];
#pragma unroll
      for (int n = 0; n < 4; ++n)
#pragma unroll
        for (int r = 0; r < 4; ++r) mx = fmaxf(mx, sa[n][r]);
      mx = fmaxf(mx, __shfl_xor(mx, 16, 64));
      mx = fmaxf(mx, __shfl_xor(mx, 32, 64));

      if (!__all(mx <= m)) {
        float mn = fmaxf(m, mx);
        float ra = exp2f((m - mn) * C2);
        m = mn;
        l *= ra;
#pragma unroll
        for (int n = 0; n < 4; ++n) {
          acc_o[n][0] *= ra; acc_o[n][1] *= ra;
          acc_o[n][2] *= ra; acc_o[n][3] *= ra;
        }
      }
      const float mC2 = m * C2;
      float pv[4][4];
      float rs = 0.f;
#pragma unroll
      for (int n = 0; n < 4; ++n)
#pragma unroll
        for (int r = 0; r < 4; ++r) {
          pv[n][r] = exp2f(fmaf(sa[n][r], C2, -mC2));
          rs += pv[n][r];
        }
      rs += __shfl_xor(rs, 16, 64);
      rs += __shfl_xor(rs, 32, 64);
      l += rs;

      // ---- P -> LDS (group-private 64 rows), packed b64 writes ----
#pragma unroll
      for (int n = 0; n < 4; ++n) {
        uint2v pk;
        pk.x = cvtpk_bf16(pv[n][0], pv[n][1]);
        pk.y = cvtpk_bf16(pv[n][2], pv[n][3]);
        *(uint2v*)&Ps[((grp << 6) + qw * 16 + ccol) * PV_STRIDE + n * 16 + crow] = pk;
      }
      __builtin_amdgcn_wave_barrier();

      // ---- PV (A=V^T, B=P) -> O[q=ccol][d=n*16+crow+r] ----
      __builtin_amdgcn_s_setprio(1);
#pragma unroll
      for (int c = 0; c < 2; ++c) {
        short8 ap = *(const short8*)&Ps[((grp << 6) + qw * 16 + frow) * PV_STRIDE + c * 32 + fg * 8];
#pragma unroll
        for (int n = 0; n < 4; ++n) {
          short8 bv = *(const short8*)&Vt[(n * 16 + frow) * PV_STRIDE + c * 32 + fg * 8];
          acc_o[n] = __builtin_amdgcn_mfma_f32_16x16x32_bf16(bv, ap, acc_o[n], 0, 0, 0);
        }
      }
      __builtin_amdgcn_s_setprio(0);
      __builtin_amdgcn_wave_barrier();
    }
  }

  // ---- epilogue: lane owns q-row (q0+qw*16+ccol), d = n*16+crow+r ----
  const float inv = 1.f / l;
  const size_t obase = (size_t)(rowbase + q0 + qw * 16 + ccol) * 1024 + (h << 6);
#pragma unroll
  for (int n = 0; n < 4; ++n) {
    uint2v pk;
    pk.x = cvtpk_bf16(acc_o[n][0] * inv, acc_o[n][1] * inv);
    pk.y = cvtpk_bf16(acc_o[n][2] * inv, acc_o[n][3] * inv);
    *(uint2v*)&aob[obase + n * 16 + crow] = pk;
  }
}

// ---------------------------------------------------------------------------
extern "C" void kernel_launch(void* const* d_in, const int* in_sizes, int n_in,
                              void* d_out, int out_size, void* d_ws, size_t ws_size,
                              hipStream_t stream) {
  const float* x        = (const float*)d_in[0];
  const float* w_cq     = (const float*)d_in[1];
  const float* w_q_nope = (const float*)d_in[2];
  const float* w_q_rope = (const float*)d_in[3];
  const float* q_g      = (const float*)d_in[4];
  const float* w_ckv    = (const float*)d_in[5];
  const float* w_k_nope = (const float*)d_in[6];
  const float* w_v      = (const float*)d_in[7];
  const float* kv_g     = (const float*)d_in[8];
  const float* w_k_rope = (const float*)d_in[9];
  const float* w_proj   = (const float*)d_in[10];
  float* out = (float*)d_out;

  // ---- workspace layout (bf16) ----
  char* w = (char*)d_ws;
  unsigned short* xb    = (unsigned short*)w; w += (size_t)ROWS * 2048 * 2;
  unsigned short* cqb   = (unsigned short*)w; w += (size_t)ROWS * QRANK * 2;
  unsigned short* ckvb  = (unsigned short*)w; w += (size_t)ROWS * KVRANK * 2;
  unsigned short* qnb   = (unsigned short*)w; w += (size_t)ROWS * 1024 * 2;
  unsigned short* qrb   = (unsigned short*)w; w += (size_t)ROWS * 512 * 2;
  unsigned short* knb   = (unsigned short*)w; w += (size_t)ROWS * 1024 * 2;
  unsigned short* vvb   = (unsigned short*)w; w += (size_t)ROWS * 1024 * 2;
  unsigned short* vvT   = (unsigned short*)w; w += (size_t)1024 * ROWS * 2;
  unsigned short* krb   = (unsigned short*)w; w += (size_t)ROWS * 32 * 2;
  unsigned short* aob   = (unsigned short*)w; w += (size_t)ROWS * 1024 * 2;
  unsigned short* wcqT  = (unsigned short*)w; w += (size_t)QRANK * 2048 * 2;
  unsigned short* wqnT  = (unsigned short*)w; w += (size_t)1024 * QRANK * 2;
  unsigned short* wqrT  = (unsigned short*)w; w += (size_t)512 * QRANK * 2;
  unsigned short* wckvT = (unsigned short*)w; w += (size_t)KVRANK * 2048 * 2;
  unsigned short* wknT  = (unsigned short*)w; w += (size_t)1024 * KVRANK * 2;
  unsigned short* wvT   = (unsigned short*)w; w += (size_t)1024 * KVRANK * 2;
  unsigned short* wprojT= (unsigned short*)w; w += (size_t)2048 * 1024 * 2;
  unsigned short* wkrT  = (unsigned short*)w; w += (size_t)32 * 2048 * 2;

  // ---- casts & weight transposes ----
  cast_to_bf16<<<ROWS * 2048 / (256 * 8), 256, 0, stream>>>(x, xb, ROWS * 2048);
  transpose_cast<<<dim3(QRANK / 32, 2048 / 32), 256, 0, stream>>>(w_cq, wcqT, 2048, QRANK);
  transpose_cast<<<dim3(1024 / 32, QRANK / 32), 256, 0, stream>>>(w_q_nope, wqnT, QRANK, 1024);
  transpose_cast<<<dim3(512 / 32, QRANK / 32), 256, 0, stream>>>(w_q_rope, wqrT, QRANK, 512);
  transpose_cast<<<dim3(KVRANK / 32, 2048 / 32), 256, 0, stream>>>(w_ckv, wckvT, 2048, KVRANK);
  transpose_cast<<<dim3(1024 / 32, KVRANK / 32), 256, 0, stream>>>(w_k_nope, wknT, KVRANK, 1024);
  transpose_cast<<<dim3(1024 / 32, KVRANK / 32), 256, 0, stream>>>(w_v, wvT, KVRANK, 1024);
  transpose_cast<<<dim3(2048 / 32, 1024 / 32), 256, 0, stream>>>(w_proj, wprojT, 1024, 2048);
  transpose_cast<<<dim3(32 / 32, 2048 / 32), 256, 0, stream>>>(w_k_rope, wkrT, 2048, 32);

  // ---- projections (bf16 MFMA, bf16 outputs) ----
  gemm_bf16<<<dim3(QRANK / 128, ROWS / 128), 256, 0, stream>>>(xb, wcqT, cqb, ROWS, QRANK, 2048, 1);
  rmsnorm_bf16<<<ROWS, 256, 0, stream>>>(cqb, q_g, QRANK, 1.0f / QRANK);
  gemm_bf16<<<dim3(1024 / 128, ROWS / 128), 256, 0, stream>>>(cqb, wqnT, qnb, ROWS, 1024, QRANK, 1);
  gemm_bf16<<<dim3(512 / 128, ROWS / 128), 256, 0, stream>>>(cqb, wqrT, qrb, ROWS, 512, QRANK, 1);
  rope_q_bf16<<<ROWS, 256, 0, stream>>>(qrb);
  gemm_bf16<<<dim3(KVRANK / 128, ROWS / 128), 256, 0, stream>>>(xb, wckvT, ckvb, ROWS, KVRANK, 2048, 1);
  rmsnorm_bf16<<<ROWS, 256, 0, stream>>>(ckvb, kv_g, KVRANK, 1.0f / KVRANK);
  gemm_bf16<<<dim3(1024 / 128, ROWS / 128), 256, 0, stream>>>(ckvb, wknT, knb, ROWS, 1024, KVRANK, 1);
  gemm_bf16<<<dim3(1024 / 128, ROWS / 128), 256, 0, stream>>>(ckvb, wvT, vvb, ROWS, 1024, KVRANK, 1);
  transpose_bf16<<<dim3(1024 / 32, ROWS / 32), 256, 0, stream>>>(vvb, vvT, ROWS, 1024);
  gemm_kr_rope<<<ROWS / 64, 256, 0, stream>>>(xb, wkrT, krb);

  // ---- attention (MFMA flash, dual-tile 8-wave) ----
  attn_mfma<<<dim3(16, 32), 512, 0, stream>>>(qnb, qrb, knb, krb, vvT, aob);

  // ---- output projection ----
  gemm_bf16<<<dim3(2048 / 128, ROWS / 128), 256, 0, stream>>>(aob, wprojT, out, ROWS, 2048, 1024, 0);
}

// Round 9
// 305.787 us; speedup vs baseline: 1.2541x; 1.1000x over previous
//
#include <hip/hip_runtime.h>
#include <hip/hip_bf16.h>
#include <math.h>

#define B_      2
#define S_      2048
#define D_      2048
#define H_      16
#define NOPE_D  64
#define ROPE_DD 32
#define V_DD    64
#define QRANK   768
#define KVRANK  256
#define ROWS    (B_ * S_)   // 4096

typedef __attribute__((ext_vector_type(8))) short short8;
typedef __attribute__((ext_vector_type(4))) float f32x4;
typedef __attribute__((ext_vector_type(4))) unsigned short ushort4v;
typedef __attribute__((ext_vector_type(2))) unsigned int uint2v;

__device__ __forceinline__ float bf2f(unsigned short u) {
  return __uint_as_float(((unsigned)u) << 16);
}
__device__ __forceinline__ unsigned short f2bf(float f) {  // RNE
  unsigned u = __float_as_uint(f);
  return (unsigned short)((u + 0x7fffu + ((u >> 16) & 1u)) >> 16);
}
__device__ __forceinline__ unsigned cvtpk_bf16(float lo, float hi) {
  unsigned r;
  asm("v_cvt_pk_bf16_f32 %0, %1, %2" : "=v"(r) : "v"(lo), "v"(hi));
  return r;
}
// async global->LDS, 16B per lane; LDS dest = wave-uniform base + lane*16
__device__ __forceinline__ void glds16(const unsigned short* g, unsigned short* l) {
  __builtin_amdgcn_global_load_lds(
      (const __attribute__((address_space(1))) unsigned int*)g,
      (__attribute__((address_space(3))) unsigned int*)l, 16, 0, 0);
}

// ---------------------------------------------------------------------------
// cast fp32 -> bf16, 8 elems/thread
// ---------------------------------------------------------------------------
__global__ __launch_bounds__(256) void cast_to_bf16(const float* __restrict__ in,
                                                    unsigned short* __restrict__ out,
                                                    int n) {
  int i = (blockIdx.x * 256 + threadIdx.x) * 8;
  if (i >= n) return;
  float4 a = *(const float4*)(in + i);
  float4 b = *(const float4*)(in + i + 4);
  unsigned short r[8] = {f2bf(a.x), f2bf(a.y), f2bf(a.z), f2bf(a.w),
                         f2bf(b.x), f2bf(b.y), f2bf(b.z), f2bf(b.w)};
  *(ushort4v*)(out + i)     = *(ushort4v*)&r[0];
  *(ushort4v*)(out + i + 4) = *(ushort4v*)&r[4];
}

// ---------------------------------------------------------------------------
// Batched transpose+cast: 8 jobs in one launch. in [R][C] f32 -> out [C][R] bf16.
// ---------------------------------------------------------------------------
struct TJobs {
  const float* in[8];
  unsigned short* out[8];
  int R[8], C[8], start[8];
};
__global__ __launch_bounds__(256) void transpose_cast_batch(TJobs j) {
  __shared__ unsigned short t[32][33];
  const int bid = blockIdx.x;
  int k = 0;
#pragma unroll
  for (int i = 1; i < 8; ++i)
    if (bid >= j.start[i]) k = i;
  const float* in = j.in[k];
  unsigned short* out = j.out[k];
  const int R = j.R[k], C = j.C[k];
  const int lb = bid - j.start[k];
  const int nbx = C >> 5;
  const int c0 = (lb % nbx) * 32, r0 = (lb / nbx) * 32;
  const int tx = threadIdx.x & 31, ty = threadIdx.x >> 5;
#pragma unroll
  for (int i = 0; i < 32; i += 8)
    t[ty + i][tx] = f2bf(in[(size_t)(r0 + ty + i) * C + c0 + tx]);
  __syncthreads();
#pragma unroll
  for (int i = 0; i < 32; i += 8)
    out[(size_t)(c0 + ty + i) * R + r0 + tx] = t[tx][ty + i];
}

// ---------------------------------------------------------------------------
// transpose bf16: in [R][C] -> out [C][R]
// ---------------------------------------------------------------------------
__global__ __launch_bounds__(256) void transpose_bf16(const unsigned short* __restrict__ in,
                                                      unsigned short* __restrict__ out,
                                                      int R, int C) {
  __shared__ unsigned short t[32][33];
  const int c0 = blockIdx.x * 32, r0 = blockIdx.y * 32;
  const int tx = threadIdx.x & 31, ty = threadIdx.x >> 5;
#pragma unroll
  for (int i = 0; i < 32; i += 8)
    t[ty + i][tx] = in[(size_t)(r0 + ty + i) * C + c0 + tx];
  __syncthreads();
#pragma unroll
  for (int i = 0; i < 32; i += 8)
    out[(size_t)(c0 + ty + i) * R + r0 + tx] = t[tx][ty + i];
}

// ---------------------------------------------------------------------------
// bf16 MFMA GEMM (TN): A [M][K] bf16, Bt [N][K] bf16, C [M][N] (f32 or bf16).
// M%128==0, N%128==0, K%32==0. 256 thr = 4 waves, tile 128x128, BK=32.
// Staging via global_load_lds (16B/lane): LDS linear; XOR granule swizzle is
// applied on the per-lane GLOBAL source addr; reads use the same swizzle.
// ---------------------------------------------------------------------------
__global__ __launch_bounds__(256) void gemm_bf16(const unsigned short* __restrict__ A,
                                                 const unsigned short* __restrict__ Bt,
                                                 void* __restrict__ Cv,
                                                 int M, int N, int K, int c_bf16) {
  __shared__ unsigned short As[128 * 32];
  __shared__ unsigned short Bs[128 * 32];
  const int tid = threadIdx.x;
  const int lane = tid & 63;
  const int wave = tid >> 6;
  const int wm = (wave >> 1) << 6;
  const int wn = (wave & 1) << 6;
  const int m0 = blockIdx.y * 128, n0 = blockIdx.x * 128;

  // staging geometry: wave w covers rows [w*32, w*32+32) in two 16-row chunks.
  // lane l -> row chunk0: w*32 + (l>>2), slot l&3; source granule = slot ^ (row&3)
  const int r0s = wave * 32 + (lane >> 2);
  const int r1s = r0s + 16;
  const int sslot = lane & 3;
  const size_t a_src0 = (size_t)(m0 + r0s) * K + (sslot ^ (r0s & 3)) * 8;
  const size_t a_src1 = (size_t)(m0 + r1s) * K + (sslot ^ (r1s & 3)) * 8;
  const size_t b_src0 = (size_t)(n0 + r0s) * K + (sslot ^ (r0s & 3)) * 8;
  const size_t b_src1 = (size_t)(n0 + r1s) * K + (sslot ^ (r1s & 3)) * 8;
  unsigned short* as0 = &As[(wave * 32) * 32];
  unsigned short* as1 = &As[(wave * 32 + 16) * 32];
  unsigned short* bs0 = &Bs[(wave * 32) * 32];
  unsigned short* bs1 = &Bs[(wave * 32 + 16) * 32];

  const int frow = lane & 15, fg = lane >> 4;
  int a_roff[4], b_roff[4];
#pragma unroll
  for (int m = 0; m < 4; ++m) {
    int r = wm + m * 16 + frow;
    a_roff[m] = r * 64 + ((fg ^ (r & 3)) << 4);
  }
#pragma unroll
  for (int n = 0; n < 4; ++n) {
    int r = wn + n * 16 + frow;
    b_roff[n] = r * 64 + ((fg ^ (r & 3)) << 4);
  }

  f32x4 acc[4][4];
#pragma unroll
  for (int m = 0; m < 4; ++m)
#pragma unroll
    for (int n = 0; n < 4; ++n) acc[m][n] = (f32x4){0.f, 0.f, 0.f, 0.f};

  for (int k0 = 0; k0 < K; k0 += 32) {
    __syncthreads();  // prior iteration's LDS reads complete
    glds16(A + a_src0 + k0, as0);
    glds16(A + a_src1 + k0, as1);
    glds16(Bt + b_src0 + k0, bs0);
    glds16(Bt + b_src1 + k0, bs1);
    __syncthreads();  // compiler drains vmcnt before barrier -> data visible
    short8 af[4], bfr[4];
#pragma unroll
    for (int m = 0; m < 4; ++m) af[m] = *(const short8*)((const char*)As + a_roff[m]);
#pragma unroll
    for (int n = 0; n < 4; ++n) bfr[n] = *(const short8*)((const char*)Bs + b_roff[n]);
#pragma unroll
    for (int m = 0; m < 4; ++m)
#pragma unroll
      for (int n = 0; n < 4; ++n)
        acc[m][n] = __builtin_amdgcn_mfma_f32_16x16x32_bf16(af[m], bfr[n], acc[m][n], 0, 0, 0);
  }

  const int crow = (lane >> 4) * 4;
  const int ccol = lane & 15;
  if (c_bf16) {
    unsigned short* Cb = (unsigned short*)Cv;
#pragma unroll
    for (int m = 0; m < 4; ++m)
#pragma unroll
      for (int n = 0; n < 4; ++n)
#pragma unroll
        for (int r = 0; r < 4; ++r)
          Cb[(size_t)(m0 + wm + m * 16 + crow + r) * N + n0 + wn + n * 16 + ccol] =
              f2bf(acc[m][n][r]);
  } else {
    float* Cf = (float*)Cv;
#pragma unroll
    for (int m = 0; m < 4; ++m)
#pragma unroll
      for (int n = 0; n < 4; ++n)
#pragma unroll
        for (int r = 0; r < 4; ++r)
          Cf[(size_t)(m0 + wm + m * 16 + crow + r) * N + n0 + wn + n * 16 + ccol] =
              acc[m][n][r];
  }
}

// ---------------------------------------------------------------------------
// In-place RMSNorm on bf16 buffer
// ---------------------------------------------------------------------------
__global__ __launch_bounds__(256) void rmsnorm_bf16(unsigned short* __restrict__ x,
                                                    const float* __restrict__ g,
                                                    int cols, float inv_cols) {
  const int row = blockIdx.x;
  unsigned short* p = x + (size_t)row * cols;
  float ss = 0.f;
  for (int c = threadIdx.x; c < cols; c += 256) { float v = bf2f(p[c]); ss += v * v; }
#pragma unroll
  for (int off = 32; off >= 1; off >>= 1) ss += __shfl_xor(ss, off, 64);
  __shared__ float wsum[4];
  if ((threadIdx.x & 63) == 0) wsum[threadIdx.x >> 6] = ss;
  __syncthreads();
  float tot = (wsum[0] + wsum[1]) + (wsum[2] + wsum[3]);
  float r = rsqrtf(tot * inv_cols + 1e-6f);
  for (int c = threadIdx.x; c < cols; c += 256) p[c] = f2bf(bf2f(p[c]) * r * g[c]);
}

// ---------------------------------------------------------------------------
// RoPE on bf16 q_rope [4096][512]. Reference's sin table == cos table.
// ---------------------------------------------------------------------------
__global__ __launch_bounds__(256) void rope_q_bf16(unsigned short* __restrict__ qr) {
  const int row = blockIdx.x;
  const int t = threadIdx.x;
  const int h = t >> 4, i = t & 15;
  const int pos = row & (S_ - 1);
  float freq = exp2f(-0.8304820237218406f * (float)i);
  float c = cosf((float)pos * freq);
  unsigned* p = (unsigned*)(qr + (size_t)row * 512 + h * 32 + 2 * i);
  unsigned v = *p;
  float xr = bf2f((unsigned short)(v & 0xffffu));
  float xi = bf2f((unsigned short)(v >> 16));
  unsigned short o0 = f2bf((xr - xi) * c);
  unsigned short o1 = f2bf((xr + xi) * c);
  *p = (unsigned)o0 | ((unsigned)o1 << 16);
}

// ---------------------------------------------------------------------------
// k_rope as MFMA GEMM + fused rope epilogue
// ---------------------------------------------------------------------------
__global__ __launch_bounds__(256) void gemm_kr_rope(
    const unsigned short* __restrict__ xb,   // [4096][2048]
    const unsigned short* __restrict__ wkrT, // [32][2048]
    unsigned short* __restrict__ krb) {      // [4096][32]
  __shared__ unsigned short As[64 * 64];
  __shared__ unsigned short Bs[32 * 64];
  const int tid = threadIdx.x;
  const int lane = tid & 63;
  const int wave = tid >> 6;
  const int m0 = blockIdx.x * 64;
  const int frow = lane & 15, fg = lane >> 4;

  const int arow = tid >> 2;
  const int ag = (tid & 3) * 2;
  const int brow = tid >> 3;
  const int bg = tid & 7;

  f32x4 acc[2];
  acc[0] = (f32x4){0.f, 0.f, 0.f, 0.f};
  acc[1] = (f32x4){0.f, 0.f, 0.f, 0.f};

  for (int k0 = 0; k0 < 2048; k0 += 64) {
    uint4 va0 = *(const uint4*)&xb[(size_t)(m0 + arow) * 2048 + k0 + ag * 8];
    uint4 va1 = *(const uint4*)&xb[(size_t)(m0 + arow) * 2048 + k0 + ag * 8 + 8];
    uint4 vb  = *(const uint4*)&wkrT[(size_t)brow * 2048 + k0 + bg * 8];
    __syncthreads();
    *(uint4*)((char*)As + arow * 128 + ((ag ^ (arow & 7)) << 4))       = va0;
    *(uint4*)((char*)As + arow * 128 + (((ag + 1) ^ (arow & 7)) << 4)) = va1;
    *(uint4*)((char*)Bs + brow * 128 + ((bg ^ (brow & 7)) << 4))       = vb;
    __syncthreads();
#pragma unroll
    for (int kk = 0; kk < 2; ++kk) {
      const int ar = wave * 16 + frow;
      short8 aq = *(const short8*)((const char*)As + ar * 128 + (((kk * 4 + fg) ^ (ar & 7)) << 4));
#pragma unroll
      for (int n = 0; n < 2; ++n) {
        const int br = n * 16 + frow;
        short8 bk = *(const short8*)((const char*)Bs + br * 128 + (((kk * 4 + fg) ^ (br & 7)) << 4));
        acc[n] = __builtin_amdgcn_mfma_f32_16x16x32_bf16(aq, bk, acc[n], 0, 0, 0);
      }
    }
  }
  const int ccol = lane & 15, crow = (lane >> 4) * 4;
#pragma unroll
  for (int n = 0; n < 2; ++n) {
    const int col = n * 16 + ccol;
    const int i = col >> 1;
    const float freq = exp2f(-0.8304820237218406f * (float)i);
#pragma unroll
    for (int r = 0; r < 4; ++r) {
      const int row = m0 + wave * 16 + crow + r;
      float v = acc[n][r] * (1.0f / 16.0f);
      float other = __shfl_xor(v, 1, 64);
      float c = cosf((float)(row & (S_ - 1)) * freq);
      float outv = (col & 1) ? (other + v) * c : (v - other) * c;
      krb[(size_t)row * 32 + col] = f2bf(outv);
    }
  }
}

// ---------------------------------------------------------------------------
// MFMA flash attention, dual-tile 8-wave blocks, lane-local softmax, T13.
// ---------------------------------------------------------------------------
#define QK_STRIDE 104   // 96 data + pad; 208B row
#define PV_STRIDE 72    // 64 data + pad; 144B row

__global__ __launch_bounds__(512, 4) void attn_mfma(
    const unsigned short* __restrict__ qnb,  // [4096][1024]
    const unsigned short* __restrict__ qrb,  // [4096][512]
    const unsigned short* __restrict__ knb,  // [4096][1024]
    const unsigned short* __restrict__ krb,  // [4096][32]
    const unsigned short* __restrict__ vvT,  // [1024][4096]: [h*64+d][b*2048+s]
    unsigned short* __restrict__ aob) {      // [4096][1024]
  __shared__ unsigned short Ks[64 * QK_STRIDE];
  __shared__ unsigned short Vt[64 * PV_STRIDE];
  __shared__ unsigned short Ps[128 * PV_STRIDE];
  const int tid = threadIdx.x;
  const int lane = tid & 63;
  const int wave = tid >> 6;          // 0..7
  const int grp = wave >> 2;          // 0: tile p, 1: tile 31-p
  const int qw = wave & 3;
  const int p = blockIdx.x;           // 0..15
  const int bh = blockIdx.y;
  const int b = bh >> 4, h = bh & 15;
  const size_t rowbase = (size_t)b * S_;
  const int frow = lane & 15, fg = lane >> 4;
  const int ccol = frow;
  const int crow = fg * 4;
  const float C2 = 0.10206207261596575f * 1.4426950408889634f;  // scale*log2(e)

  const int q0 = (grp ? (31 - p) : p) * 64;
  const int nkt = 32 - p;

  const size_t qrow = rowbase + q0 + qw * 16 + frow;
  short8 qf0 = *(const short8*)&qnb[qrow * 1024 + (h << 6) + fg * 8];
  short8 qf1 = *(const short8*)&qnb[qrow * 1024 + (h << 6) + 32 + fg * 8];
  short8 qf2 = *(const short8*)&qrb[qrow * 512 + (h << 5) + fg * 8];

  float m = -1e30f, l = 0.f;
  f32x4 acc_o[4];
#pragma unroll
  for (int n = 0; n < 4; ++n) acc_o[n] = (f32x4){0.f, 0.f, 0.f, 0.f};

  for (int kt = 0; kt < nkt; ++kt) {
    const int k0 = kt << 6;
    __syncthreads();
    {  // staging: 512 threads, one uint4 each for K-nope and Vt
      const int row = tid >> 3, col = (tid & 7) * 8;
      *(uint4*)&Ks[row * QK_STRIDE + col] =
          *(const uint4*)&knb[(size_t)(rowbase + k0 + row) * 1024 + (h << 6) + col];
      *(uint4*)&Vt[row * PV_STRIDE + col] =
          *(const uint4*)&vvT[(size_t)((h << 6) + row) * 4096 + b * S_ + k0 + col];
      if (tid < 256) {
        const int rr = tid >> 2, rc = (tid & 3) * 8;
        *(uint4*)&Ks[rr * QK_STRIDE + 64 + rc] =
            *(const uint4*)&krb[(size_t)(rowbase + k0 + rr) * 32 + rc];
      }
    }
    __syncthreads();

    if (k0 <= q0) {
      // ---- QK^T (A=K, B=Q-regs) -> S[q=ccol][k=n*16+crow+r] ----
      f32x4 sa[4];
#pragma unroll
      for (int n = 0; n < 4; ++n) sa[n] = (f32x4){0.f, 0.f, 0.f, 0.f};
      __builtin_amdgcn_s_setprio(1);
#pragma unroll
      for (int n = 0; n < 4; ++n) {
        short8 bk0 = *(const short8*)&Ks[(n * 16 + frow) * QK_STRIDE + fg * 8];
        short8 bk1 = *(const short8*)&Ks[(n * 16 + frow) * QK_STRIDE + 32 + fg * 8];
        short8 bk2 = *(const short8*)&Ks[(n * 16 + frow) * QK_STRIDE + 64 + fg * 8];
        sa[n] = __builtin_amdgcn_mfma_f32_16x16x32_bf16(bk0, qf0, sa[n], 0, 0, 0);
        sa[n] = __builtin_amdgcn_mfma_f32_16x16x32_bf16(bk1, qf1, sa[n], 0, 0, 0);
        sa[n] = __builtin_amdgcn_mfma_f32_16x16x32_bf16(bk2, qf2, sa[n], 0, 0, 0);
      }
      __builtin_amdgcn_s_setprio(0);
      if (k0 == q0) {
        const int qloc = qw * 16 + ccol;
#pragma unroll
        for (int n = 0; n < 4; ++n)
#pragma unroll
          for (int r = 0; r < 4; ++r)
            if (n * 16 + crow + r > qloc) sa[n][r] = -1e30f;
      }

      // ---- online softmax: in-lane over 16 + 2 shfl; T13 defer-max ----
      float mx = sa[0][0];
#pragma unroll
      for (int n = 0; n < 4; ++n)
#pragma unroll
        for (int r = 0; r < 4; ++r) mx = fmaxf(mx, sa[n][r]);
      mx = fmaxf(mx, __shfl_xor(mx, 16, 64));
      mx = fmaxf(mx, __shfl_xor(mx, 32, 64));

      if (!__all((mx - m) * C2 <= 8.0f)) {  // T13: tolerate P up to 2^8
        float mn = fmaxf(m, mx);
        float ra = exp2f((m - mn) * C2);
        m = mn;
        l *= ra;
#pragma unroll
        for (int n = 0; n < 4; ++n) {
          acc_o[n][0] *= ra; acc_o[n][1] *= ra;
          acc_o[n][2] *= ra; acc_o[n][3] *= ra;
        }
      }
      const float mC2 = m * C2;
      float pv[4][4];
      float rs = 0.f;
#pragma unroll
      for (int n = 0; n < 4; ++n)
#pragma unroll
        for (int r = 0; r < 4; ++r) {
          pv[n][r] = exp2f(fmaf(sa[n][r], C2, -mC2));
          rs += pv[n][r];
        }
      rs += __shfl_xor(rs, 16, 64);
      rs += __shfl_xor(rs, 32, 64);
      l += rs;

      // ---- P -> LDS (group-private rows), packed b64 writes ----
#pragma unroll
      for (int n = 0; n < 4; ++n) {
        uint2v pk;
        pk.x = cvtpk_bf16(pv[n][0], pv[n][1]);
        pk.y = cvtpk_bf16(pv[n][2], pv[n][3]);
        *(uint2v*)&Ps[((grp << 6) + qw * 16 + ccol) * PV_STRIDE + n * 16 + crow] = pk;
      }
      __builtin_amdgcn_wave_barrier();

      // ---- PV (A=V^T, B=P) -> O[q=ccol][d=n*16+crow+r] ----
      __builtin_amdgcn_s_setprio(1);
#pragma unroll
      for (int c = 0; c < 2; ++c) {
        short8 ap = *(const short8*)&Ps[((grp << 6) + qw * 16 + frow) * PV_STRIDE + c * 32 + fg * 8];
#pragma unroll
        for (int n = 0; n < 4; ++n) {
          short8 bv = *(const short8*)&Vt[(n * 16 + frow) * PV_STRIDE + c * 32 + fg * 8];
          acc_o[n] = __builtin_amdgcn_mfma_f32_16x16x32_bf16(bv, ap, acc_o[n], 0, 0, 0);
        }
      }
      __builtin_amdgcn_s_setprio(0);
      __builtin_amdgcn_wave_barrier();
    }
  }

  const float inv = 1.f / l;
  const size_t obase = (size_t)(rowbase + q0 + qw * 16 + ccol) * 1024 + (h << 6);
#pragma unroll
  for (int n = 0; n < 4; ++n) {
    uint2v pk;
    pk.x = cvtpk_bf16(acc_o[n][0] * inv, acc_o[n][1] * inv);
    pk.y = cvtpk_bf16(acc_o[n][2] * inv, acc_o[n][3] * inv);
    *(uint2v*)&aob[obase + n * 16 + crow] = pk;
  }
}

// ---------------------------------------------------------------------------
extern "C" void kernel_launch(void* const* d_in, const int* in_sizes, int n_in,
                              void* d_out, int out_size, void* d_ws, size_t ws_size,
                              hipStream_t stream) {
  const float* x        = (const float*)d_in[0];
  const float* w_cq     = (const float*)d_in[1];
  const float* w_q_nope = (const float*)d_in[2];
  const float* w_q_rope = (const float*)d_in[3];
  const float* q_g      = (const float*)d_in[4];
  const float* w_ckv    = (const float*)d_in[5];
  const float* w_k_nope = (const float*)d_in[6];
  const float* w_v      = (const float*)d_in[7];
  const float* kv_g     = (const float*)d_in[8];
  const float* w_k_rope = (const float*)d_in[9];
  const float* w_proj   = (const float*)d_in[10];
  float* out = (float*)d_out;

  // ---- workspace layout (bf16) ----
  char* w = (char*)d_ws;
  unsigned short* xb    = (unsigned short*)w; w += (size_t)ROWS * 2048 * 2;
  unsigned short* cqb   = (unsigned short*)w; w += (size_t)ROWS * QRANK * 2;
  unsigned short* ckvb  = (unsigned short*)w; w += (size_t)ROWS * KVRANK * 2;
  unsigned short* qnb   = (unsigned short*)w; w += (size_t)ROWS * 1024 * 2;
  unsigned short* qrb   = (unsigned short*)w; w += (size_t)ROWS * 512 * 2;
  unsigned short* knb   = (unsigned short*)w; w += (size_t)ROWS * 1024 * 2;
  unsigned short* vvb   = (unsigned short*)w; w += (size_t)ROWS * 1024 * 2;
  unsigned short* vvT   = (unsigned short*)w; w += (size_t)1024 * ROWS * 2;
  unsigned short* krb   = (unsigned short*)w; w += (size_t)ROWS * 32 * 2;
  unsigned short* aob   = (unsigned short*)w; w += (size_t)ROWS * 1024 * 2;
  unsigned short* wcqT  = (unsigned short*)w; w += (size_t)QRANK * 2048 * 2;
  unsigned short* wqnT  = (unsigned short*)w; w += (size_t)1024 * QRANK * 2;
  unsigned short* wqrT  = (unsigned short*)w; w += (size_t)512 * QRANK * 2;
  unsigned short* wckvT = (unsigned short*)w; w += (size_t)KVRANK * 2048 * 2;
  unsigned short* wknT  = (unsigned short*)w; w += (size_t)1024 * KVRANK * 2;
  unsigned short* wvT   = (unsigned short*)w; w += (size_t)1024 * KVRANK * 2;
  unsigned short* wprojT= (unsigned short*)w; w += (size_t)2048 * 1024 * 2;
  unsigned short* wkrT  = (unsigned short*)w; w += (size_t)32 * 2048 * 2;

  // ---- cast + batched weight transposes (single launch) ----
  cast_to_bf16<<<ROWS * 2048 / (256 * 8), 256, 0, stream>>>(x, xb, ROWS * 2048);
  TJobs tj;
  tj.in[0] = w_cq;     tj.out[0] = wcqT;   tj.R[0] = 2048; tj.C[0] = QRANK; tj.start[0] = 0;
  tj.in[1] = w_q_nope; tj.out[1] = wqnT;   tj.R[1] = QRANK;tj.C[1] = 1024;  tj.start[1] = 1536;
  tj.in[2] = w_q_rope; tj.out[2] = wqrT;   tj.R[2] = QRANK;tj.C[2] = 512;   tj.start[2] = 2304;
  tj.in[3] = w_ckv;    tj.out[3] = wckvT;  tj.R[3] = 2048; tj.C[3] = KVRANK;tj.start[3] = 2688;
  tj.in[4] = w_k_nope; tj.out[4] = wknT;   tj.R[4] = KVRANK;tj.C[4] = 1024; tj.start[4] = 3200;
  tj.in[5] = w_v;      tj.out[5] = wvT;    tj.R[5] = KVRANK;tj.C[5] = 1024; tj.start[5] = 3456;
  tj.in[6] = w_proj;   tj.out[6] = wprojT; tj.R[6] = 1024; tj.C[6] = 2048;  tj.start[6] = 3712;
  tj.in[7] = w_k_rope; tj.out[7] = wkrT;   tj.R[7] = 2048; tj.C[7] = 32;    tj.start[7] = 5760;
  transpose_cast_batch<<<5824, 256, 0, stream>>>(tj);

  // ---- projections (bf16 MFMA, bf16 outputs) ----
  gemm_bf16<<<dim3(QRANK / 128, ROWS / 128), 256, 0, stream>>>(xb, wcqT, cqb, ROWS, QRANK, 2048, 1);
  rmsnorm_bf16<<<ROWS, 256, 0, stream>>>(cqb, q_g, QRANK, 1.0f / QRANK);
  gemm_bf16<<<dim3(1024 / 128, ROWS / 128), 256, 0, stream>>>(cqb, wqnT, qnb, ROWS, 1024, QRANK, 1);
  gemm_bf16<<<dim3(512 / 128, ROWS / 128), 256, 0, stream>>>(cqb, wqrT, qrb, ROWS, 512, QRANK, 1);
  rope_q_bf16<<<ROWS, 256, 0, stream>>>(qrb);
  gemm_bf16<<<dim3(KVRANK / 128, ROWS / 128), 256, 0, stream>>>(xb, wckvT, ckvb, ROWS, KVRANK, 2048, 1);
  rmsnorm_bf16<<<ROWS, 256, 0, stream>>>(ckvb, kv_g, KVRANK, 1.0f / KVRANK);
  gemm_bf16<<<dim3(1024 / 128, ROWS / 128), 256, 0, stream>>>(ckvb, wknT, knb, ROWS, 1024, KVRANK, 1);
  gemm_bf16<<<dim3(1024 / 128, ROWS / 128), 256, 0, stream>>>(ckvb, wvT, vvb, ROWS, 1024, KVRANK, 1);
  transpose_bf16<<<dim3(1024 / 32, ROWS / 32), 256, 0, stream>>>(vvb, vvT, ROWS, 1024);
  gemm_kr_rope<<<ROWS / 64, 256, 0, stream>>>(xb, wkrT, krb);

  // ---- attention (MFMA flash, dual-tile 8-wave) ----
  attn_mfma<<<dim3(16, 32), 512, 0, stream>>>(qnb, qrb, knb, krb, vvT, aob);

  // ---- output projection ----
  gemm_bf16<<<dim3(2048 / 128, ROWS / 128), 256, 0, stream>>>(aob, wprojT, out, ROWS, 2048, 1024, 0);
}

// Round 10
// 240.625 us; speedup vs baseline: 1.5938x; 1.2708x over previous
//
#include <hip/hip_runtime.h>
#include <hip/hip_bf16.h>
#include <math.h>

#define B_      2
#define S_      2048
#define D_      2048
#define H_      16
#define QRANK   768
#define KVRANK  256
#define ROWS    (B_ * S_)   // 4096

typedef __attribute__((ext_vector_type(8))) short short8;
typedef __attribute__((ext_vector_type(4))) float f32x4;
typedef __attribute__((ext_vector_type(4))) unsigned short ushort4v;
typedef __attribute__((ext_vector_type(2))) unsigned int uint2v;

__device__ __forceinline__ float bf2f(unsigned short u) {
  return __uint_as_float(((unsigned)u) << 16);
}
__device__ __forceinline__ unsigned short f2bf(float f) {  // RNE
  unsigned u = __float_as_uint(f);
  return (unsigned short)((u + 0x7fffu + ((u >> 16) & 1u)) >> 16);
}
__device__ __forceinline__ unsigned cvtpk_bf16(float lo, float hi) {
  unsigned r;
  asm("v_cvt_pk_bf16_f32 %0, %1, %2" : "=v"(r) : "v"(lo), "v"(hi));
  return r;
}
// async global->LDS, 16B per lane; LDS dest = wave-uniform base + lane*16
__device__ __forceinline__ void glds16(const unsigned short* g, unsigned short* l) {
  __builtin_amdgcn_global_load_lds(
      (const __attribute__((address_space(1))) unsigned int*)g,
      (__attribute__((address_space(3))) unsigned int*)l, 16, 0, 0);
}

// ---------------------------------------------------------------------------
// cast fp32 -> bf16, 8 elems/thread
// ---------------------------------------------------------------------------
__global__ __launch_bounds__(256) void cast_to_bf16(const float* __restrict__ in,
                                                    unsigned short* __restrict__ out,
                                                    int n) {
  int i = (blockIdx.x * 256 + threadIdx.x) * 8;
  if (i >= n) return;
  float4 a = *(const float4*)(in + i);
  float4 b = *(const float4*)(in + i + 4);
  unsigned short r[8] = {f2bf(a.x), f2bf(a.y), f2bf(a.z), f2bf(a.w),
                         f2bf(b.x), f2bf(b.y), f2bf(b.z), f2bf(b.w)};
  *(ushort4v*)(out + i)     = *(ushort4v*)&r[0];
  *(ushort4v*)(out + i + 4) = *(ushort4v*)&r[4];
}

// ---------------------------------------------------------------------------
// Batched transpose+cast: 8 jobs in one launch. in [R][C] f32 -> out [C][R] bf16.
// ---------------------------------------------------------------------------
struct TJobs {
  const float* in[8];
  unsigned short* out[8];
  int R[8], C[8], start[8];
};
__global__ __launch_bounds__(256) void transpose_cast_batch(TJobs j) {
  __shared__ unsigned short t[32][33];
  const int bid = blockIdx.x;
  int k = 0;
#pragma unroll
  for (int i = 1; i < 8; ++i)
    if (bid >= j.start[i]) k = i;
  const float* in = j.in[k];
  unsigned short* out = j.out[k];
  const int R = j.R[k], C = j.C[k];
  const int lb = bid - j.start[k];
  const int nbx = C >> 5;
  const int c0 = (lb % nbx) * 32, r0 = (lb / nbx) * 32;
  const int tx = threadIdx.x & 31, ty = threadIdx.x >> 5;
#pragma unroll
  for (int i = 0; i < 32; i += 8)
    t[ty + i][tx] = f2bf(in[(size_t)(r0 + ty + i) * C + c0 + tx]);
  __syncthreads();
#pragma unroll
  for (int i = 0; i < 32; i += 8)
    out[(size_t)(c0 + ty + i) * R + r0 + tx] = t[tx][ty + i];
}

// ---------------------------------------------------------------------------
// bf16 MFMA GEMM (TN): A [M][K] (row stride lda), Bt [N][K] (row stride ldb),
// C [M][N] f32 or bf16. M%128==0, N%128==0, K%32==0. 256 thr, 128x128, BK=32.
// global_load_lds staging: LDS linear; XOR granule swizzle on the per-lane
// GLOBAL source address; fragment reads use the same swizzle.
// ---------------------------------------------------------------------------
__global__ __launch_bounds__(256) void gemm_bf16(const unsigned short* __restrict__ A,
                                                 int lda,
                                                 const unsigned short* __restrict__ Bt,
                                                 int ldb,
                                                 void* __restrict__ Cv,
                                                 int M, int N, int K, int c_bf16) {
  __shared__ unsigned short As[128 * 32];
  __shared__ unsigned short Bs[128 * 32];
  const int tid = threadIdx.x;
  const int lane = tid & 63;
  const int wave = tid >> 6;
  const int wm = (wave >> 1) << 6;
  const int wn = (wave & 1) << 6;
  const int m0 = blockIdx.y * 128, n0 = blockIdx.x * 128;

  const int r0s = wave * 32 + (lane >> 2);
  const int r1s = r0s + 16;
  const int sslot = lane & 3;
  const size_t a_src0 = (size_t)(m0 + r0s) * lda + (sslot ^ (r0s & 3)) * 8;
  const size_t a_src1 = (size_t)(m0 + r1s) * lda + (sslot ^ (r1s & 3)) * 8;
  const size_t b_src0 = (size_t)(n0 + r0s) * ldb + (sslot ^ (r0s & 3)) * 8;
  const size_t b_src1 = (size_t)(n0 + r1s) * ldb + (sslot ^ (r1s & 3)) * 8;
  unsigned short* as0 = &As[(wave * 32) * 32];
  unsigned short* as1 = &As[(wave * 32 + 16) * 32];
  unsigned short* bs0 = &Bs[(wave * 32) * 32];
  unsigned short* bs1 = &Bs[(wave * 32 + 16) * 32];

  const int frow = lane & 15, fg = lane >> 4;
  int a_roff[4], b_roff[4];
#pragma unroll
  for (int m = 0; m < 4; ++m) {
    int r = wm + m * 16 + frow;
    a_roff[m] = r * 64 + ((fg ^ (r & 3)) << 4);
  }
#pragma unroll
  for (int n = 0; n < 4; ++n) {
    int r = wn + n * 16 + frow;
    b_roff[n] = r * 64 + ((fg ^ (r & 3)) << 4);
  }

  f32x4 acc[4][4];
#pragma unroll
  for (int m = 0; m < 4; ++m)
#pragma unroll
    for (int n = 0; n < 4; ++n) acc[m][n] = (f32x4){0.f, 0.f, 0.f, 0.f};

  for (int k0 = 0; k0 < K; k0 += 32) {
    __syncthreads();
    glds16(A + a_src0 + k0, as0);
    glds16(A + a_src1 + k0, as1);
    glds16(Bt + b_src0 + k0, bs0);
    glds16(Bt + b_src1 + k0, bs1);
    __syncthreads();
    short8 af[4], bfr[4];
#pragma unroll
    for (int m = 0; m < 4; ++m) af[m] = *(const short8*)((const char*)As + a_roff[m]);
#pragma unroll
    for (int n = 0; n < 4; ++n) bfr[n] = *(const short8*)((const char*)Bs + b_roff[n]);
#pragma unroll
    for (int m = 0; m < 4; ++m)
#pragma unroll
      for (int n = 0; n < 4; ++n)
        acc[m][n] = __builtin_amdgcn_mfma_f32_16x16x32_bf16(af[m], bfr[n], acc[m][n], 0, 0, 0);
  }

  const int crow = (lane >> 4) * 4;
  const int ccol = lane & 15;
  if (c_bf16) {
    unsigned short* Cb = (unsigned short*)Cv;
#pragma unroll
    for (int m = 0; m < 4; ++m)
#pragma unroll
      for (int n = 0; n < 4; ++n)
#pragma unroll
        for (int r = 0; r < 4; ++r)
          Cb[(size_t)(m0 + wm + m * 16 + crow + r) * N + n0 + wn + n * 16 + ccol] =
              f2bf(acc[m][n][r]);
  } else {
    float* Cf = (float*)Cv;
#pragma unroll
    for (int m = 0; m < 4; ++m)
#pragma unroll
      for (int n = 0; n < 4; ++n)
#pragma unroll
        for (int r = 0; r < 4; ++r)
          Cf[(size_t)(m0 + wm + m * 16 + crow + r) * N + n0 + wn + n * 16 + ccol] =
              acc[m][n][r];
  }
}

// ---------------------------------------------------------------------------
// In-place RMSNorm on bf16 buffer segment (row stride ldx)
// ---------------------------------------------------------------------------
__global__ __launch_bounds__(256) void rmsnorm_bf16(unsigned short* __restrict__ x,
                                                    const float* __restrict__ g,
                                                    int cols, float inv_cols, int ldx) {
  const int row = blockIdx.x;
  unsigned short* p = x + (size_t)row * ldx;
  float ss = 0.f;
  for (int c = threadIdx.x; c < cols; c += 256) { float v = bf2f(p[c]); ss += v * v; }
#pragma unroll
  for (int off = 32; off >= 1; off >>= 1) ss += __shfl_xor(ss, off, 64);
  __shared__ float wsum[4];
  if ((threadIdx.x & 63) == 0) wsum[threadIdx.x >> 6] = ss;
  __syncthreads();
  float tot = (wsum[0] + wsum[1]) + (wsum[2] + wsum[3]);
  float r = rsqrtf(tot * inv_cols + 1e-6f);
  for (int c = threadIdx.x; c < cols; c += 256) p[c] = f2bf(bf2f(p[c]) * r * g[c]);
}

// ---------------------------------------------------------------------------
// RoPE on bf16 q_rope segment (row stride ldx; 512 cols). sin == cos table.
// ---------------------------------------------------------------------------
__global__ __launch_bounds__(256) void rope_q_bf16(unsigned short* __restrict__ qr, int ldx) {
  const int row = blockIdx.x;
  const int t = threadIdx.x;
  const int h = t >> 4, i = t & 15;
  const int pos = row & (S_ - 1);
  float freq = exp2f(-0.8304820237218406f * (float)i);
  float c = cosf((float)pos * freq);
  unsigned* p = (unsigned*)(qr + (size_t)row * ldx + h * 32 + 2 * i);
  unsigned v = *p;
  float xr = bf2f((unsigned short)(v & 0xffffu));
  float xi = bf2f((unsigned short)(v >> 16));
  unsigned short o0 = f2bf((xr - xi) * c);
  unsigned short o1 = f2bf((xr + xi) * c);
  *p = (unsigned)o0 | ((unsigned)o1 << 16);
}

// ---------------------------------------------------------------------------
// k_rope as MFMA GEMM + fused rope epilogue
// ---------------------------------------------------------------------------
__global__ __launch_bounds__(256) void gemm_kr_rope(
    const unsigned short* __restrict__ xb,   // [4096][2048]
    const unsigned short* __restrict__ wkrT, // [32][2048]
    unsigned short* __restrict__ krb) {      // [4096][32]
  __shared__ unsigned short As[64 * 64];
  __shared__ unsigned short Bs[32 * 64];
  const int tid = threadIdx.x;
  const int lane = tid & 63;
  const int wave = tid >> 6;
  const int m0 = blockIdx.x * 64;
  const int frow = lane & 15, fg = lane >> 4;

  const int arow = tid >> 2;
  const int ag = (tid & 3) * 2;
  const int brow = tid >> 3;
  const int bg = tid & 7;

  f32x4 acc[2];
  acc[0] = (f32x4){0.f, 0.f, 0.f, 0.f};
  acc[1] = (f32x4){0.f, 0.f, 0.f, 0.f};

  for (int k0 = 0; k0 < 2048; k0 += 64) {
    uint4 va0 = *(const uint4*)&xb[(size_t)(m0 + arow) * 2048 + k0 + ag * 8];
    uint4 va1 = *(const uint4*)&xb[(size_t)(m0 + arow) * 2048 + k0 + ag * 8 + 8];
    uint4 vb  = *(const uint4*)&wkrT[(size_t)brow * 2048 + k0 + bg * 8];
    __syncthreads();
    *(uint4*)((char*)As + arow * 128 + ((ag ^ (arow & 7)) << 4))       = va0;
    *(uint4*)((char*)As + arow * 128 + (((ag + 1) ^ (arow & 7)) << 4)) = va1;
    *(uint4*)((char*)Bs + brow * 128 + ((bg ^ (brow & 7)) << 4))       = vb;
    __syncthreads();
#pragma unroll
    for (int kk = 0; kk < 2; ++kk) {
      const int ar = wave * 16 + frow;
      short8 aq = *(const short8*)((const char*)As + ar * 128 + (((kk * 4 + fg) ^ (ar & 7)) << 4));
#pragma unroll
      for (int n = 0; n < 2; ++n) {
        const int br = n * 16 + frow;
        short8 bk = *(const short8*)((const char*)Bs + br * 128 + (((kk * 4 + fg) ^ (br & 7)) << 4));
        acc[n] = __builtin_amdgcn_mfma_f32_16x16x32_bf16(aq, bk, acc[n], 0, 0, 0);
      }
    }
  }
  const int ccol = lane & 15, crow = (lane >> 4) * 4;
#pragma unroll
  for (int n = 0; n < 2; ++n) {
    const int col = n * 16 + ccol;
    const int i = col >> 1;
    const float freq = exp2f(-0.8304820237218406f * (float)i);
#pragma unroll
    for (int r = 0; r < 4; ++r) {
      const int row = m0 + wave * 16 + crow + r;
      float v = acc[n][r] * (1.0f / 16.0f);
      float other = __shfl_xor(v, 1, 64);
      float c = cosf((float)(row & (S_ - 1)) * freq);
      float outv = (col & 1) ? (other + v) * c : (v - other) * c;
      krb[(size_t)row * 32 + col] = f2bf(outv);
    }
  }
}

// ---------------------------------------------------------------------------
// MFMA flash attention, dual-tile 8-wave blocks, lane-local softmax, T13,
// T14 async-stage + LDS double-buffer (issue loads early, commit after barrier).
// ---------------------------------------------------------------------------
#define QK_STRIDE 104   // 96 data + pad; 208B row
#define PV_STRIDE 72    // 64 data + pad; 144B row
#define QQ_LD 1536      // merged qn|qr row stride

__global__ __launch_bounds__(512, 4) void attn_mfma(
    const unsigned short* __restrict__ qq,   // [4096][1536]: qn | qr
    const unsigned short* __restrict__ knb,  // [4096][1024]
    const unsigned short* __restrict__ krb,  // [4096][32]
    const unsigned short* __restrict__ vvT,  // [1024][4096]: [h*64+d][b*2048+s]
    unsigned short* __restrict__ aob) {      // [4096][1024]
  __shared__ unsigned short Ks[2][64 * QK_STRIDE];
  __shared__ unsigned short Vt[2][64 * PV_STRIDE];
  __shared__ unsigned short Ps[128 * PV_STRIDE];
  const int tid = threadIdx.x;
  const int lane = tid & 63;
  const int wave = tid >> 6;          // 0..7
  const int grp = wave >> 2;          // 0: tile p, 1: tile 31-p
  const int qw = wave & 3;
  const int p = blockIdx.x;           // 0..15
  const int bh = blockIdx.y;
  const int b = bh >> 4, h = bh & 15;
  const size_t rowbase = (size_t)b * S_;
  const int frow = lane & 15, fg = lane >> 4;
  const int ccol = frow;
  const int crow = fg * 4;
  const float C2 = 0.10206207261596575f * 1.4426950408889634f;  // scale*log2(e)

  const int q0 = (grp ? (31 - p) : p) * 64;
  const int nkt = 32 - p;

  // staging geometry
  const int srow = tid >> 3, scol = (tid & 7) * 8;
  const int rrow = tid >> 2, rcol = (tid & 3) * 8;

  // Q fragments in registers (one q-row per lane, 96 dims)
  const size_t qrow = rowbase + q0 + qw * 16 + frow;
  short8 qf0 = *(const short8*)&qq[qrow * QQ_LD + (h << 6) + fg * 8];
  short8 qf1 = *(const short8*)&qq[qrow * QQ_LD + (h << 6) + 32 + fg * 8];
  short8 qf2 = *(const short8*)&qq[qrow * QQ_LD + 1024 + (h << 5) + fg * 8];

  float m = -1e30f, l = 0.f;
  f32x4 acc_o[4];
#pragma unroll
  for (int n = 0; n < 4; ++n) acc_o[n] = (f32x4){0.f, 0.f, 0.f, 0.f};

  uint4 kreg, vreg, rreg;
  auto ISSUE = [&](int kt) {
    const int k0v = kt << 6;
    kreg = *(const uint4*)&knb[(size_t)(rowbase + k0v + srow) * 1024 + (h << 6) + scol];
    vreg = *(const uint4*)&vvT[(size_t)((h << 6) + srow) * 4096 + b * S_ + k0v + scol];
    if (tid < 256)
      rreg = *(const uint4*)&krb[(size_t)(rowbase + k0v + rrow) * 32 + rcol];
  };
  auto COMMIT = [&](int bsel) {
    *(uint4*)&Ks[bsel][srow * QK_STRIDE + scol] = kreg;
    *(uint4*)&Vt[bsel][srow * PV_STRIDE + scol] = vreg;
    if (tid < 256)
      *(uint4*)&Ks[bsel][rrow * QK_STRIDE + 64 + rcol] = rreg;
  };

  ISSUE(0);
  COMMIT(0);
  __syncthreads();

  for (int kt = 0; kt < nkt; ++kt) {
    if (kt + 1 < nkt) ISSUE(kt + 1);       // loads in flight during compute
    const int k0 = kt << 6;
    const int cur = kt & 1;
    if (k0 <= q0) {
      const unsigned short* Kc = Ks[cur];
      const unsigned short* Vc = Vt[cur];
      // ---- QK^T (A=K, B=Q-regs) -> S[q=ccol][k=n*16+crow+r] ----
      f32x4 sa[4];
#pragma unroll
      for (int n = 0; n < 4; ++n) sa[n] = (f32x4){0.f, 0.f, 0.f, 0.f};
      __builtin_amdgcn_s_setprio(1);
#pragma unroll
      for (int n = 0; n < 4; ++n) {
        short8 bk0 = *(const short8*)&Kc[(n * 16 + frow) * QK_STRIDE + fg * 8];
        short8 bk1 = *(const short8*)&Kc[(n * 16 + frow) * QK_STRIDE + 32 + fg * 8];
        short8 bk2 = *(const short8*)&Kc[(n * 16 + frow) * QK_STRIDE + 64 + fg * 8];
        sa[n] = __builtin_amdgcn_mfma_f32_16x16x32_bf16(bk0, qf0, sa[n], 0, 0, 0);
        sa[n] = __builtin_amdgcn_mfma_f32_16x16x32_bf16(bk1, qf1, sa[n], 0, 0, 0);
        sa[n] = __builtin_amdgcn_mfma_f32_16x16x32_bf16(bk2, qf2, sa[n], 0, 0, 0);
      }
      __builtin_amdgcn_s_setprio(0);
      if (k0 == q0) {
        const int qloc = qw * 16 + ccol;
#pragma unroll
        for (int n = 0; n < 4; ++n)
#pragma unroll
          for (int r = 0; r < 4; ++r)
            if (n * 16 + crow + r > qloc) sa[n][r] = -1e30f;
      }

      // ---- online softmax: in-lane over 16 + 2 shfl; T13 defer-max ----
      float mx = sa[0][0];
#pragma unroll
      for (int n = 0; n < 4; ++n)
#pragma unroll
        for (int r = 0; r < 4; ++r) mx = fmaxf(mx, sa[n][r]);
      mx = fmaxf(mx, __shfl_xor(mx, 16, 64));
      mx = fmaxf(mx, __shfl_xor(mx, 32, 64));

      if (!__all((mx - m) * C2 <= 8.0f)) {
        float mn = fmaxf(m, mx);
        float ra = exp2f((m - mn) * C2);
        m = mn;
        l *= ra;
#pragma unroll
        for (int n = 0; n < 4; ++n) {
          acc_o[n][0] *= ra; acc_o[n][1] *= ra;
          acc_o[n][2] *= ra; acc_o[n][3] *= ra;
        }
      }
      const float mC2 = m * C2;
      float pvv[4][4];
      float rs = 0.f;
#pragma unroll
      for (int n = 0; n < 4; ++n)
#pragma unroll
        for (int r = 0; r < 4; ++r) {
          pvv[n][r] = exp2f(fmaf(sa[n][r], C2, -mC2));
          rs += pvv[n][r];
        }
      rs += __shfl_xor(rs, 16, 64);
      rs += __shfl_xor(rs, 32, 64);
      l += rs;

      // ---- P -> LDS (group-private rows), packed b64 writes ----
#pragma unroll
      for (int n = 0; n < 4; ++n) {
        uint2v pk;
        pk.x = cvtpk_bf16(pvv[n][0], pvv[n][1]);
        pk.y = cvtpk_bf16(pvv[n][2], pvv[n][3]);
        *(uint2v*)&Ps[((grp << 6) + qw * 16 + ccol) * PV_STRIDE + n * 16 + crow] = pk;
      }
      __builtin_amdgcn_wave_barrier();

      // ---- PV (A=V^T, B=P) -> O[q=ccol][d=n*16+crow+r] ----
      __builtin_amdgcn_s_setprio(1);
#pragma unroll
      for (int c = 0; c < 2; ++c) {
        short8 ap = *(const short8*)&Ps[((grp << 6) + qw * 16 + frow) * PV_STRIDE + c * 32 + fg * 8];
#pragma unroll
        for (int n = 0; n < 4; ++n) {
          short8 bv = *(const short8*)&Vc[(n * 16 + frow) * PV_STRIDE + c * 32 + fg * 8];
          acc_o[n] = __builtin_amdgcn_mfma_f32_16x16x32_bf16(bv, ap, acc_o[n], 0, 0, 0);
        }
      }
      __builtin_amdgcn_s_setprio(0);
      __builtin_amdgcn_wave_barrier();
    }
    __syncthreads();                        // all reads of buf[cur^1] long done; reads of buf[cur] done
    if (kt + 1 < nkt) COMMIT((kt + 1) & 1); // vmcnt wait inserted by compiler
    __syncthreads();
  }

  const float inv = 1.f / l;
  const size_t obase = (size_t)(rowbase + q0 + qw * 16 + ccol) * 1024 + (h << 6);
#pragma unroll
  for (int n = 0; n < 4; ++n) {
    uint2v pk;
    pk.x = cvtpk_bf16(acc_o[n][0] * inv, acc_o[n][1] * inv);
    pk.y = cvtpk_bf16(acc_o[n][2] * inv, acc_o[n][3] * inv);
    *(uint2v*)&aob[obase + n * 16 + crow] = pk;
  }
}

// ---------------------------------------------------------------------------
extern "C" void kernel_launch(void* const* d_in, const int* in_sizes, int n_in,
                              void* d_out, int out_size, void* d_ws, size_t ws_size,
                              hipStream_t stream) {
  const float* x        = (const float*)d_in[0];
  const float* w_cq     = (const float*)d_in[1];
  const float* w_q_nope = (const float*)d_in[2];
  const float* w_q_rope = (const float*)d_in[3];
  const float* q_g      = (const float*)d_in[4];
  const float* w_ckv    = (const float*)d_in[5];
  const float* w_k_nope = (const float*)d_in[6];
  const float* w_v      = (const float*)d_in[7];
  const float* kv_g     = (const float*)d_in[8];
  const float* w_k_rope = (const float*)d_in[9];
  const float* w_proj   = (const float*)d_in[10];
  float* out = (float*)d_out;

  // ---- workspace layout (bf16) ----
  char* w = (char*)d_ws;
  unsigned short* xb    = (unsigned short*)w; w += (size_t)ROWS * 2048 * 2;
  unsigned short* cc    = (unsigned short*)w; w += (size_t)ROWS * 1024 * 2;  // cq|ckv
  unsigned short* qq    = (unsigned short*)w; w += (size_t)ROWS * 1536 * 2;  // qn|qr
  unsigned short* knb   = (unsigned short*)w; w += (size_t)ROWS * 1024 * 2;
  unsigned short* vvT   = (unsigned short*)w; w += (size_t)1024 * ROWS * 2;
  unsigned short* krb   = (unsigned short*)w; w += (size_t)ROWS * 32 * 2;
  unsigned short* aob   = (unsigned short*)w; w += (size_t)ROWS * 1024 * 2;
  // merged weight blocks (concats must be adjacent!)
  unsigned short* wcqT  = (unsigned short*)w; w += (size_t)QRANK * 2048 * 2;   // [768][2048]
  unsigned short* wckvT = (unsigned short*)w; w += (size_t)KVRANK * 2048 * 2;  // [256][2048]
  unsigned short* wqnT  = (unsigned short*)w; w += (size_t)1024 * QRANK * 2;   // [1024][768]
  unsigned short* wqrT  = (unsigned short*)w; w += (size_t)512 * QRANK * 2;    // [512][768]
  unsigned short* wknT  = (unsigned short*)w; w += (size_t)1024 * KVRANK * 2;
  unsigned short* wvT   = (unsigned short*)w; w += (size_t)1024 * KVRANK * 2;
  unsigned short* wprojT= (unsigned short*)w; w += (size_t)2048 * 1024 * 2;
  unsigned short* wkrT  = (unsigned short*)w; w += (size_t)32 * 2048 * 2;

  // ---- cast + batched weight transposes ----
  cast_to_bf16<<<ROWS * 2048 / (256 * 8), 256, 0, stream>>>(x, xb, ROWS * 2048);
  TJobs tj;
  tj.in[0] = w_cq;     tj.out[0] = wcqT;   tj.R[0] = 2048; tj.C[0] = QRANK;  tj.start[0] = 0;
  tj.in[1] = w_q_nope; tj.out[1] = wqnT;   tj.R[1] = QRANK;tj.C[1] = 1024;   tj.start[1] = 1536;
  tj.in[2] = w_q_rope; tj.out[2] = wqrT;   tj.R[2] = QRANK;tj.C[2] = 512;    tj.start[2] = 2304;
  tj.in[3] = w_ckv;    tj.out[3] = wckvT;  tj.R[3] = 2048; tj.C[3] = KVRANK; tj.start[3] = 2688;
  tj.in[4] = w_k_nope; tj.out[4] = wknT;   tj.R[4] = KVRANK;tj.C[4] = 1024;  tj.start[4] = 3200;
  tj.in[5] = w_v;      tj.out[5] = wvT;    tj.R[5] = KVRANK;tj.C[5] = 1024;  tj.start[5] = 3456;
  tj.in[6] = w_proj;   tj.out[6] = wprojT; tj.R[6] = 1024; tj.C[6] = 2048;   tj.start[6] = 3712;
  tj.in[7] = w_k_rope; tj.out[7] = wkrT;   tj.R[7] = 2048; tj.C[7] = 32;     tj.start[7] = 5760;
  transpose_cast_batch<<<5824, 256, 0, stream>>>(tj);

  // ---- cc = x @ [w_cq | w_ckv]  (N=1024, 256 blocks) ----
  gemm_bf16<<<dim3(1024 / 128, ROWS / 128), 256, 0, stream>>>(
      xb, 2048, wcqT, 2048, cc, ROWS, 1024, 2048, 1);
  rmsnorm_bf16<<<ROWS, 256, 0, stream>>>(cc, q_g, QRANK, 1.0f / QRANK, 1024);
  rmsnorm_bf16<<<ROWS, 256, 0, stream>>>(cc + QRANK, kv_g, KVRANK, 1.0f / KVRANK, 1024);

  // ---- qq = cq @ [w_q_nope | w_q_rope]  (N=1536, 384 blocks) ----
  gemm_bf16<<<dim3(1536 / 128, ROWS / 128), 256, 0, stream>>>(
      cc, 1024, wqnT, QRANK, qq, ROWS, 1536, QRANK, 1);
  rope_q_bf16<<<ROWS, 256, 0, stream>>>(qq + 1024, QQ_LD);

  // ---- kn = ckv @ w_k_nope  (N=1024, 256 blocks) ----
  gemm_bf16<<<dim3(1024 / 128, ROWS / 128), 256, 0, stream>>>(
      cc + QRANK, 1024, wknT, KVRANK, knb, ROWS, 1024, KVRANK, 1);
  // ---- vvT = w_v^T @ ckv^T  (M=1024, N=4096 -> [d][token] directly) ----
  gemm_bf16<<<dim3(ROWS / 128, 1024 / 128), 256, 0, stream>>>(
      wvT, KVRANK, cc + QRANK, 1024, vvT, 1024, ROWS, KVRANK, 1);
  // ---- kr ----
  gemm_kr_rope<<<ROWS / 64, 256, 0, stream>>>(xb, wkrT, krb);

  // ---- attention ----
  attn_mfma<<<dim3(16, 32), 512, 0, stream>>>(qq, knb, krb, vvT, aob);

  // ---- output projection ----
  gemm_bf16<<<dim3(2048 / 128, ROWS / 128), 256, 0, stream>>>(
      aob, 1024, wprojT, 1024, out, ROWS, 2048, 1024, 0);
}

// Round 11
// 215.740 us; speedup vs baseline: 1.7776x; 1.1153x over previous
//
#include <hip/hip_runtime.h>
#include <hip/hip_bf16.h>
#include <math.h>

#define B_      2
#define S_      2048
#define D_      2048
#define H_      16
#define QRANK   768
#define KVRANK  256
#define ROWS    (B_ * S_)   // 4096
#define CC_LD   1152        // cq(768) | ckv(256) | kr_raw(32) | pad(96)
#define QQ_LD   1536        // qn(1024) | qr(512)

typedef __attribute__((ext_vector_type(8))) short short8;
typedef __attribute__((ext_vector_type(4))) float f32x4;
typedef __attribute__((ext_vector_type(4))) unsigned short ushort4v;
typedef __attribute__((ext_vector_type(2))) unsigned int uint2v;

__device__ __forceinline__ float bf2f(unsigned short u) {
  return __uint_as_float(((unsigned)u) << 16);
}
__device__ __forceinline__ unsigned short f2bf(float f) {  // RNE
  unsigned u = __float_as_uint(f);
  return (unsigned short)((u + 0x7fffu + ((u >> 16) & 1u)) >> 16);
}
__device__ __forceinline__ unsigned cvtpk_bf16(float lo, float hi) {
  unsigned r;
  asm("v_cvt_pk_bf16_f32 %0, %1, %2" : "=v"(r) : "v"(lo), "v"(hi));
  return r;
}
__device__ __forceinline__ void glds16(const unsigned short* g, unsigned short* l) {
  __builtin_amdgcn_global_load_lds(
      (const __attribute__((address_space(1))) unsigned int*)g,
      (__attribute__((address_space(3))) unsigned int*)l, 16, 0, 0);
}

// ---------------------------------------------------------------------------
// cast fp32 -> bf16, 8 elems/thread
// ---------------------------------------------------------------------------
__global__ __launch_bounds__(256) void cast_to_bf16(const float* __restrict__ in,
                                                    unsigned short* __restrict__ out,
                                                    int n) {
  int i = (blockIdx.x * 256 + threadIdx.x) * 8;
  if (i >= n) return;
  float4 a = *(const float4*)(in + i);
  float4 b = *(const float4*)(in + i + 4);
  unsigned short r[8] = {f2bf(a.x), f2bf(a.y), f2bf(a.z), f2bf(a.w),
                         f2bf(b.x), f2bf(b.y), f2bf(b.z), f2bf(b.w)};
  *(ushort4v*)(out + i)     = *(ushort4v*)&r[0];
  *(ushort4v*)(out + i + 4) = *(ushort4v*)&r[4];
}

// ---------------------------------------------------------------------------
// Batched transpose+cast: 8 jobs in one launch. in [R][C] f32 -> out [C][R] bf16.
// ---------------------------------------------------------------------------
struct TJobs {
  const float* in[8];
  unsigned short* out[8];
  int R[8], C[8], start[8];
};
__global__ __launch_bounds__(256) void transpose_cast_batch(TJobs j) {
  __shared__ unsigned short t[32][33];
  const int bid = blockIdx.x;
  int k = 0;
#pragma unroll
  for (int i = 1; i < 8; ++i)
    if (bid >= j.start[i]) k = i;
  const float* in = j.in[k];
  unsigned short* out = j.out[k];
  const int R = j.R[k], C = j.C[k];
  const int lb = bid - j.start[k];
  const int nbx = C >> 5;
  const int c0 = (lb % nbx) * 32, r0 = (lb / nbx) * 32;
  const int tx = threadIdx.x & 31, ty = threadIdx.x >> 5;
#pragma unroll
  for (int i = 0; i < 32; i += 8)
    t[ty + i][tx] = f2bf(in[(size_t)(r0 + ty + i) * C + c0 + tx]);
  __syncthreads();
#pragma unroll
  for (int i = 0; i < 32; i += 8)
    out[(size_t)(c0 + ty + i) * R + r0 + tx] = t[tx][ty + i];
}

// ---------------------------------------------------------------------------
// bf16 MFMA GEMM (TN): A [M][K] (row stride lda), Bt [N][K] (row stride ldb),
// C [M][N] f32 or bf16. 256 thr, 128x128 tile, BK=32, global_load_lds staging.
// ---------------------------------------------------------------------------
__global__ __launch_bounds__(256) void gemm_bf16(const unsigned short* __restrict__ A,
                                                 int lda,
                                                 const unsigned short* __restrict__ Bt,
                                                 int ldb,
                                                 void* __restrict__ Cv,
                                                 int M, int N, int K, int c_bf16) {
  __shared__ unsigned short As[128 * 32];
  __shared__ unsigned short Bs[128 * 32];
  const int tid = threadIdx.x;
  const int lane = tid & 63;
  const int wave = tid >> 6;
  const int wm = (wave >> 1) << 6;
  const int wn = (wave & 1) << 6;
  const int m0 = blockIdx.y * 128, n0 = blockIdx.x * 128;

  const int r0s = wave * 32 + (lane >> 2);
  const int r1s = r0s + 16;
  const int sslot = lane & 3;
  const size_t a_src0 = (size_t)(m0 + r0s) * lda + (sslot ^ (r0s & 3)) * 8;
  const size_t a_src1 = (size_t)(m0 + r1s) * lda + (sslot ^ (r1s & 3)) * 8;
  const size_t b_src0 = (size_t)(n0 + r0s) * ldb + (sslot ^ (r0s & 3)) * 8;
  const size_t b_src1 = (size_t)(n0 + r1s) * ldb + (sslot ^ (r1s & 3)) * 8;
  unsigned short* as0 = &As[(wave * 32) * 32];
  unsigned short* as1 = &As[(wave * 32 + 16) * 32];
  unsigned short* bs0 = &Bs[(wave * 32) * 32];
  unsigned short* bs1 = &Bs[(wave * 32 + 16) * 32];

  const int frow = lane & 15, fg = lane >> 4;
  int a_roff[4], b_roff[4];
#pragma unroll
  for (int m = 0; m < 4; ++m) {
    int r = wm + m * 16 + frow;
    a_roff[m] = r * 64 + ((fg ^ (r & 3)) << 4);
  }
#pragma unroll
  for (int n = 0; n < 4; ++n) {
    int r = wn + n * 16 + frow;
    b_roff[n] = r * 64 + ((fg ^ (r & 3)) << 4);
  }

  f32x4 acc[4][4];
#pragma unroll
  for (int m = 0; m < 4; ++m)
#pragma unroll
    for (int n = 0; n < 4; ++n) acc[m][n] = (f32x4){0.f, 0.f, 0.f, 0.f};

  for (int k0 = 0; k0 < K; k0 += 32) {
    __syncthreads();
    glds16(A + a_src0 + k0, as0);
    glds16(A + a_src1 + k0, as1);
    glds16(Bt + b_src0 + k0, bs0);
    glds16(Bt + b_src1 + k0, bs1);
    __syncthreads();
    short8 af[4], bfr[4];
#pragma unroll
    for (int m = 0; m < 4; ++m) af[m] = *(const short8*)((const char*)As + a_roff[m]);
#pragma unroll
    for (int n = 0; n < 4; ++n) bfr[n] = *(const short8*)((const char*)Bs + b_roff[n]);
#pragma unroll
    for (int m = 0; m < 4; ++m)
#pragma unroll
      for (int n = 0; n < 4; ++n)
        acc[m][n] = __builtin_amdgcn_mfma_f32_16x16x32_bf16(af[m], bfr[n], acc[m][n], 0, 0, 0);
  }

  const int crow = (lane >> 4) * 4;
  const int ccol = lane & 15;
  if (c_bf16) {
    unsigned short* Cb = (unsigned short*)Cv;
#pragma unroll
    for (int m = 0; m < 4; ++m)
#pragma unroll
      for (int n = 0; n < 4; ++n)
#pragma unroll
        for (int r = 0; r < 4; ++r)
          Cb[(size_t)(m0 + wm + m * 16 + crow + r) * N + n0 + wn + n * 16 + ccol] =
              f2bf(acc[m][n][r]);
  } else {
    float* Cf = (float*)Cv;
#pragma unroll
    for (int m = 0; m < 4; ++m)
#pragma unroll
      for (int n = 0; n < 4; ++n)
#pragma unroll
        for (int r = 0; r < 4; ++r)
          Cf[(size_t)(m0 + wm + m * 16 + crow + r) * N + n0 + wn + n * 16 + ccol] =
              acc[m][n][r];
  }
}

// ---------------------------------------------------------------------------
// Fused double RMSNorm: row segments [0,768) with q_g and [768,1024) with kv_g
// ---------------------------------------------------------------------------
__global__ __launch_bounds__(256) void rmsnorm2_bf16(unsigned short* __restrict__ cc,
                                                     const float* __restrict__ qg,
                                                     const float* __restrict__ kvg) {
  const int row = blockIdx.x;
  unsigned short* p = cc + (size_t)row * CC_LD;
  const int tid = threadIdx.x;
  __shared__ float w1[4], w2[4];
  float ss = 0.f;
  for (int c = tid; c < QRANK; c += 256) { float v = bf2f(p[c]); ss += v * v; }
  float s2 = 0.f;
  { float v = bf2f(p[QRANK + tid]); s2 = v * v; }
#pragma unroll
  for (int off = 32; off >= 1; off >>= 1) {
    ss += __shfl_xor(ss, off, 64);
    s2 += __shfl_xor(s2, off, 64);
  }
  if ((tid & 63) == 0) { w1[tid >> 6] = ss; w2[tid >> 6] = s2; }
  __syncthreads();
  float r1 = rsqrtf((w1[0] + w1[1] + w1[2] + w1[3]) * (1.0f / QRANK) + 1e-6f);
  float r2 = rsqrtf((w2[0] + w2[1] + w2[2] + w2[3]) * (1.0f / KVRANK) + 1e-6f);
  for (int c = tid; c < QRANK; c += 256) p[c] = f2bf(bf2f(p[c]) * r1 * qg[c]);
  { int c = QRANK + tid; p[c] = f2bf(bf2f(p[c]) * r2 * kvg[tid]); }
}

// ---------------------------------------------------------------------------
// RoPE on bf16 q_rope segment (row stride ldx; 512 cols). sin == cos table.
// ---------------------------------------------------------------------------
__global__ __launch_bounds__(256) void rope_q_bf16(unsigned short* __restrict__ qr, int ldx) {
  const int row = blockIdx.x;
  const int t = threadIdx.x;
  const int h = t >> 4, i = t & 15;
  const int pos = row & (S_ - 1);
  float freq = exp2f(-0.8304820237218406f * (float)i);
  float c = cosf((float)pos * freq);
  unsigned* p = (unsigned*)(qr + (size_t)row * ldx + h * 32 + 2 * i);
  unsigned v = *p;
  float xr = bf2f((unsigned short)(v & 0xffffu));
  float xi = bf2f((unsigned short)(v >> 16));
  unsigned short o0 = f2bf((xr - xi) * c);
  unsigned short o1 = f2bf((xr + xi) * c);
  *p = (unsigned)o0 | ((unsigned)o1 << 16);
}

// ---------------------------------------------------------------------------
// k_rope finish: krb[row][2i,2i+1] = rope(cc[row][1024+2i,1024+2i+1] / 16)
// 16 rows per block, 16 pairs per row.
// ---------------------------------------------------------------------------
__global__ __launch_bounds__(256) void rope_kr(const unsigned short* __restrict__ cc,
                                               unsigned short* __restrict__ krb) {
  const int row = blockIdx.x * 16 + (threadIdx.x >> 4);
  const int i = threadIdx.x & 15;
  const int pos = row & (S_ - 1);
  float freq = exp2f(-0.8304820237218406f * (float)i);
  float c = cosf((float)pos * freq);
  unsigned v = *(const unsigned*)(cc + (size_t)row * CC_LD + 1024 + 2 * i);
  float xr = bf2f((unsigned short)(v & 0xffffu)) * (1.0f / 16.0f);
  float xi = bf2f((unsigned short)(v >> 16)) * (1.0f / 16.0f);
  unsigned short o0 = f2bf((xr - xi) * c);
  unsigned short o1 = f2bf((xr + xi) * c);
  *(unsigned*)(krb + (size_t)row * 32 + 2 * i) =
      (unsigned)o0 | ((unsigned)o1 << 16);
}

// ---------------------------------------------------------------------------
// MFMA flash attention: dual-tile 8-wave blocks, lane-local softmax, T13,
// reg-prefetch staging, KVBLK=128 (halves barriers + rescales per column).
// ---------------------------------------------------------------------------
#define KS_ST 104   // 96 data + pad (208B row, 2-way bank max)
#define VT_ST 136   // 128 data + pad (272B row)
#define PS_ST 136

__global__ __launch_bounds__(512, 4) void attn_mfma(
    const unsigned short* __restrict__ qq,   // [4096][1536]: qn | qr
    const unsigned short* __restrict__ knb,  // [4096][1024]
    const unsigned short* __restrict__ krb,  // [4096][32]
    const unsigned short* __restrict__ vvT,  // [1024][4096]: [h*64+d][b*2048+s]
    unsigned short* __restrict__ aob) {      // [4096][1024]
  __shared__ unsigned short Ks[128 * KS_ST];  // 26.6 KB
  __shared__ unsigned short Vt[64 * VT_ST];   // 17.4 KB
  __shared__ unsigned short Ps[128 * PS_ST];  // 34.8 KB
  const int tid = threadIdx.x;
  const int lane = tid & 63;
  const int wave = tid >> 6;          // 0..7
  const int grp = wave >> 2;          // 0: tile p, 1: tile 31-p
  const int qw = wave & 3;
  const int p = blockIdx.x;           // 0..15
  const int bh = blockIdx.y;
  const int b = bh >> 4, h = bh & 15;
  const size_t rowbase = (size_t)b * S_;
  const int frow = lane & 15, fg = lane >> 4;
  const int ccol = frow;
  const int crow = fg * 4;
  const float C2 = 0.10206207261596575f * 1.4426950408889634f;  // scale*log2(e)

  const int q0 = (grp ? (31 - p) : p) * 64;
  const int nkt = (((31 - p) * 64 + 63) >> 7) + 1;  // k-tiles for the big tile

  // staging geometry (512 threads)
  const int k_r = tid >> 3, k_c = (tid & 7) * 8;    // K-nope rows k_r, k_r+64; Vt row k_r
  const int r_r = tid >> 2, r_c = (tid & 3) * 8;    // k-rope row (0..127)

  // Q fragments in registers (one q-row per lane, 96 dims)
  const size_t qrow = rowbase + q0 + qw * 16 + frow;
  short8 qf0 = *(const short8*)&qq[qrow * QQ_LD + (h << 6) + fg * 8];
  short8 qf1 = *(const short8*)&qq[qrow * QQ_LD + (h << 6) + 32 + fg * 8];
  short8 qf2 = *(const short8*)&qq[qrow * QQ_LD + 1024 + (h << 5) + fg * 8];

  float m = -1e30f, l = 0.f;
  f32x4 acc_o[4];
#pragma unroll
  for (int n = 0; n < 4; ++n) acc_o[n] = (f32x4){0.f, 0.f, 0.f, 0.f};

  uint4 kreg0, kreg1, rreg, vreg0, vreg1;
  auto ISSUE = [&](int kt) {
    const int k0v = kt << 7;
    kreg0 = *(const uint4*)&knb[(size_t)(rowbase + k0v + k_r) * 1024 + (h << 6) + k_c];
    kreg1 = *(const uint4*)&knb[(size_t)(rowbase + k0v + k_r + 64) * 1024 + (h << 6) + k_c];
    rreg  = *(const uint4*)&krb[(size_t)(rowbase + k0v + r_r) * 32 + r_c];
    vreg0 = *(const uint4*)&vvT[(size_t)((h << 6) + k_r) * 4096 + b * S_ + k0v + k_c];
    vreg1 = *(const uint4*)&vvT[(size_t)((h << 6) + k_r) * 4096 + b * S_ + k0v + 64 + k_c];
  };
  auto COMMIT = [&]() {
    *(uint4*)&Ks[k_r * KS_ST + k_c] = kreg0;
    *(uint4*)&Ks[(k_r + 64) * KS_ST + k_c] = kreg1;
    *(uint4*)&Ks[r_r * KS_ST + 64 + r_c] = rreg;
    *(uint4*)&Vt[k_r * VT_ST + k_c] = vreg0;
    *(uint4*)&Vt[k_r * VT_ST + 64 + k_c] = vreg1;
  };

  ISSUE(0);
  COMMIT();
  __syncthreads();

  for (int kt = 0; kt < nkt; ++kt) {
    if (kt + 1 < nkt) ISSUE(kt + 1);     // loads in flight during compute
    const int k0 = kt << 7;
    if (k0 <= q0 + 63) {
      // ---- QK^T (A=K, B=Q-regs) -> S[q=ccol][k=n*16+crow+r], n=0..7 ----
      f32x4 sa[8];
#pragma unroll
      for (int n = 0; n < 8; ++n) sa[n] = (f32x4){0.f, 0.f, 0.f, 0.f};
      __builtin_amdgcn_s_setprio(1);
#pragma unroll
      for (int n = 0; n < 8; ++n) {
        short8 bk0 = *(const short8*)&Ks[(n * 16 + frow) * KS_ST + fg * 8];
        short8 bk1 = *(const short8*)&Ks[(n * 16 + frow) * KS_ST + 32 + fg * 8];
        short8 bk2 = *(const short8*)&Ks[(n * 16 + frow) * KS_ST + 64 + fg * 8];
        sa[n] = __builtin_amdgcn_mfma_f32_16x16x32_bf16(bk0, qf0, sa[n], 0, 0, 0);
        sa[n] = __builtin_amdgcn_mfma_f32_16x16x32_bf16(bk1, qf1, sa[n], 0, 0, 0);
        sa[n] = __builtin_amdgcn_mfma_f32_16x16x32_bf16(bk2, qf2, sa[n], 0, 0, 0);
      }
      __builtin_amdgcn_s_setprio(0);
      if (k0 + 127 > q0) {  // tile reaches past some q -> causal mask (global idx)
        const int qg = q0 + qw * 16 + ccol;
#pragma unroll
        for (int n = 0; n < 8; ++n)
#pragma unroll
          for (int r = 0; r < 4; ++r)
            if (k0 + n * 16 + crow + r > qg) sa[n][r] = -1e30f;
      }

      // ---- online softmax: in-lane over 32 + 2 shfl; T13 defer-max ----
      float mx = sa[0][0];
#pragma unroll
      for (int n = 0; n < 8; ++n)
#pragma unroll
        for (int r = 0; r < 4; ++r) mx = fmaxf(mx, sa[n][r]);
      mx = fmaxf(mx, __shfl_xor(mx, 16, 64));
      mx = fmaxf(mx, __shfl_xor(mx, 32, 64));

      if (!__all((mx - m) * C2 <= 8.0f)) {
        float mn = fmaxf(m, mx);
        float ra = exp2f((m - mn) * C2);
        m = mn;
        l *= ra;
#pragma unroll
        for (int n = 0; n < 4; ++n) {
          acc_o[n][0] *= ra; acc_o[n][1] *= ra;
          acc_o[n][2] *= ra; acc_o[n][3] *= ra;
        }
      }
      const float mC2 = m * C2;
      float rs = 0.f;
      const int prow = ((grp << 6) + qw * 16 + ccol) * PS_ST;
#pragma unroll
      for (int n = 0; n < 8; ++n) {
        float p0 = exp2f(fmaf(sa[n][0], C2, -mC2));
        float p1 = exp2f(fmaf(sa[n][1], C2, -mC2));
        float p2 = exp2f(fmaf(sa[n][2], C2, -mC2));
        float p3 = exp2f(fmaf(sa[n][3], C2, -mC2));
        rs += (p0 + p1) + (p2 + p3);
        uint2v pk;
        pk.x = cvtpk_bf16(p0, p1);
        pk.y = cvtpk_bf16(p2, p3);
        *(uint2v*)&Ps[prow + n * 16 + crow] = pk;
      }
      rs += __shfl_xor(rs, 16, 64);
      rs += __shfl_xor(rs, 32, 64);
      l += rs;
      __builtin_amdgcn_wave_barrier();

      // ---- PV (A=V^T, B=P) -> O[q=ccol][d=n*16+crow+r] ----
      __builtin_amdgcn_s_setprio(1);
#pragma unroll
      for (int c = 0; c < 4; ++c) {
        short8 ap = *(const short8*)&Ps[((grp << 6) + qw * 16 + frow) * PS_ST + c * 32 + fg * 8];
#pragma unroll
        for (int n = 0; n < 4; ++n) {
          short8 bv = *(const short8*)&Vt[(n * 16 + frow) * VT_ST + c * 32 + fg * 8];
          acc_o[n] = __builtin_amdgcn_mfma_f32_16x16x32_bf16(bv, ap, acc_o[n], 0, 0, 0);
        }
      }
      __builtin_amdgcn_s_setprio(0);
      __builtin_amdgcn_wave_barrier();
    }
    __syncthreads();                      // all reads of Ks/Vt done
    if (kt + 1 < nkt) COMMIT();
    __syncthreads();
  }

  const float inv = 1.f / l;
  const size_t obase = (size_t)(rowbase + q0 + qw * 16 + ccol) * 1024 + (h << 6);
#pragma unroll
  for (int n = 0; n < 4; ++n) {
    uint2v pk;
    pk.x = cvtpk_bf16(acc_o[n][0] * inv, acc_o[n][1] * inv);
    pk.y = cvtpk_bf16(acc_o[n][2] * inv, acc_o[n][3] * inv);
    *(uint2v*)&aob[obase + n * 16 + crow] = pk;
  }
}

// ---------------------------------------------------------------------------
extern "C" void kernel_launch(void* const* d_in, const int* in_sizes, int n_in,
                              void* d_out, int out_size, void* d_ws, size_t ws_size,
                              hipStream_t stream) {
  const float* x        = (const float*)d_in[0];
  const float* w_cq     = (const float*)d_in[1];
  const float* w_q_nope = (const float*)d_in[2];
  const float* w_q_rope = (const float*)d_in[3];
  const float* q_g      = (const float*)d_in[4];
  const float* w_ckv    = (const float*)d_in[5];
  const float* w_k_nope = (const float*)d_in[6];
  const float* w_v      = (const float*)d_in[7];
  const float* kv_g     = (const float*)d_in[8];
  const float* w_k_rope = (const float*)d_in[9];
  const float* w_proj   = (const float*)d_in[10];
  float* out = (float*)d_out;

  // ---- workspace layout (bf16) ----
  char* w = (char*)d_ws;
  unsigned short* xb    = (unsigned short*)w; w += (size_t)ROWS * 2048 * 2;
  unsigned short* cc    = (unsigned short*)w; w += (size_t)ROWS * CC_LD * 2;   // cq|ckv|kr
  unsigned short* qq    = (unsigned short*)w; w += (size_t)ROWS * QQ_LD * 2;   // qn|qr
  unsigned short* knb   = (unsigned short*)w; w += (size_t)ROWS * 1024 * 2;
  unsigned short* vvT   = (unsigned short*)w; w += (size_t)1024 * ROWS * 2;
  unsigned short* krb   = (unsigned short*)w; w += (size_t)ROWS * 32 * 2;
  unsigned short* aob   = (unsigned short*)w; w += (size_t)ROWS * 1024 * 2;
  unsigned short* wAll  = (unsigned short*)w; w += (size_t)CC_LD * 2048 * 2;   // wcqT|wckvT|wkrT|pad
  unsigned short* wqnT  = (unsigned short*)w; w += (size_t)1024 * QRANK * 2;   // [1024][768]
  unsigned short* wqrT  = (unsigned short*)w; w += (size_t)512 * QRANK * 2;    // [512][768] (adjacent)
  unsigned short* wknT  = (unsigned short*)w; w += (size_t)1024 * KVRANK * 2;
  unsigned short* wvT   = (unsigned short*)w; w += (size_t)1024 * KVRANK * 2;
  unsigned short* wprojT= (unsigned short*)w; w += (size_t)2048 * 1024 * 2;
  unsigned short* wcqT  = wAll;                          // rows 0..767
  unsigned short* wckvT = wAll + (size_t)QRANK * 2048;   // rows 768..1023
  unsigned short* wkrT  = wAll + (size_t)1024 * 2048;    // rows 1024..1055

  // ---- cast + batched weight transposes ----
  cast_to_bf16<<<ROWS * 2048 / (256 * 8), 256, 0, stream>>>(x, xb, ROWS * 2048);
  TJobs tj;
  tj.in[0] = w_cq;     tj.out[0] = wcqT;   tj.R[0] = 2048; tj.C[0] = QRANK;  tj.start[0] = 0;
  tj.in[1] = w_q_nope; tj.out[1] = wqnT;   tj.R[1] = QRANK;tj.C[1] = 1024;   tj.start[1] = 1536;
  tj.in[2] = w_q_rope; tj.out[2] = wqrT;   tj.R[2] = QRANK;tj.C[2] = 512;    tj.start[2] = 2304;
  tj.in[3] = w_ckv;    tj.out[3] = wckvT;  tj.R[3] = 2048; tj.C[3] = KVRANK; tj.start[3] = 2688;
  tj.in[4] = w_k_nope; tj.out[4] = wknT;   tj.R[4] = KVRANK;tj.C[4] = 1024;  tj.start[4] = 3200;
  tj.in[5] = w_v;      tj.out[5] = wvT;    tj.R[5] = KVRANK;tj.C[5] = 1024;  tj.start[5] = 3456;
  tj.in[6] = w_proj;   tj.out[6] = wprojT; tj.R[6] = 1024; tj.C[6] = 2048;   tj.start[6] = 3712;
  tj.in[7] = w_k_rope; tj.out[7] = wkrT;   tj.R[7] = 2048; tj.C[7] = 32;     tj.start[7] = 5760;
  transpose_cast_batch<<<5824, 256, 0, stream>>>(tj);

  // ---- cc = x @ [w_cq | w_ckv | w_k_rope | pad]  (N=1152, 288 blocks) ----
  gemm_bf16<<<dim3(CC_LD / 128, ROWS / 128), 256, 0, stream>>>(
      xb, 2048, wAll, 2048, cc, ROWS, CC_LD, 2048, 1);
  // kr = rope(cc[:,1024:1056]/16)
  rope_kr<<<ROWS / 16, 256, 0, stream>>>(cc, krb);
  // rmsnorm both segments
  rmsnorm2_bf16<<<ROWS, 256, 0, stream>>>(cc, q_g, kv_g);

  // ---- qq = cq @ [w_q_nope | w_q_rope]  (N=1536, 384 blocks) ----
  gemm_bf16<<<dim3(QQ_LD / 128, ROWS / 128), 256, 0, stream>>>(
      cc, CC_LD, wqnT, QRANK, qq, ROWS, QQ_LD, QRANK, 1);
  rope_q_bf16<<<ROWS, 256, 0, stream>>>(qq + 1024, QQ_LD);

  // ---- kn = ckv @ w_k_nope  (N=1024, 256 blocks) ----
  gemm_bf16<<<dim3(1024 / 128, ROWS / 128), 256, 0, stream>>>(
      cc + QRANK, CC_LD, wknT, KVRANK, knb, ROWS, 1024, KVRANK, 1);
  // ---- vvT = w_v^T @ ckv^T  ([d][token] directly) ----
  gemm_bf16<<<dim3(ROWS / 128, 1024 / 128), 256, 0, stream>>>(
      wvT, KVRANK, cc + QRANK, CC_LD, vvT, 1024, ROWS, KVRANK, 1);

  // ---- attention (KVBLK=128) ----
  attn_mfma<<<dim3(16, 32), 512, 0, stream>>>(qq, knb, krb, vvT, aob);

  // ---- output projection ----
  gemm_bf16<<<dim3(2048 / 128, ROWS / 128), 256, 0, stream>>>(
      aob, 1024, wprojT, 1024, out, ROWS, 2048, 1024, 0);
}